// Round 1
// 1312.219 us; speedup vs baseline: 1.0429x; 1.0429x over previous
//
#include <hip/hip_runtime.h>
#include <math.h>

typedef unsigned short u16;
typedef __attribute__((ext_vector_type(8))) short bf16x8;
typedef __attribute__((ext_vector_type(4))) float f32x4;

#define DI __device__ __forceinline__

constexpr int Tt  = 2048;   // tokens
constexpr int Hh  = 2048;   // hidden
constexpr int DFFd = 4096;  // expert ffn dim

DI u16 f2b(float f) {
  union { float f; unsigned u; } x; x.f = f;
  unsigned r = x.u + 0x7fffu + ((x.u >> 16) & 1u);
  return (u16)(r >> 16);
}
DI float b2f(u16 h) {
  union { unsigned u; float f; } x; x.u = ((unsigned)h) << 16; return x.f;
}
DI void gll16(const void* g, void* l) {
  __builtin_amdgcn_global_load_lds((const __attribute__((address_space(1))) unsigned int*)g,
                                   (__attribute__((address_space(3))) unsigned int*)l, 16, 0, 0);
}

// ---------------- fused add + RMSNorm (ln1), with hi/lo bf16 split ----------------
__global__ void k_addnorm(const float* __restrict__ hs, const float* __restrict__ resid,
                          const float* __restrict__ w, float* __restrict__ resf,
                          u16* __restrict__ hb, u16* __restrict__ hblo) {
  const int t = blockIdx.x, tid = threadIdx.x, lane = tid & 63, wid = tid >> 6;
  __shared__ float red[4];
  const size_t base = (size_t)t * Hh;
  float4 a = *(const float4*)(hs + base + tid * 4);
  float4 b = *(const float4*)(resid + base + tid * 4);
  float4 c = *(const float4*)(hs + base + 1024 + tid * 4);
  float4 d = *(const float4*)(resid + base + 1024 + tid * 4);
  float4 r1 = {a.x + b.x, a.y + b.y, a.z + b.z, a.w + b.w};
  float4 r2 = {c.x + d.x, c.y + d.y, c.z + d.z, c.w + d.w};
  *(float4*)(resf + base + tid * 4) = r1;
  *(float4*)(resf + base + 1024 + tid * 4) = r2;
  float ss = r1.x*r1.x + r1.y*r1.y + r1.z*r1.z + r1.w*r1.w
           + r2.x*r2.x + r2.y*r2.y + r2.z*r2.z + r2.w*r2.w;
#pragma unroll
  for (int m = 1; m < 64; m <<= 1) ss += __shfl_xor(ss, m);
  if (lane == 0) red[wid] = ss;
  __syncthreads();
  float tot = red[0] + red[1] + red[2] + red[3];
  float rstd = rsqrtf(tot * (1.f / Hh) + 1e-5f);
  float4 w1v = *(const float4*)(w + tid * 4);
  float4 w2v = *(const float4*)(w + 1024 + tid * 4);
  float hv[8];
  hv[0] = r1.x * rstd * w1v.x; hv[1] = r1.y * rstd * w1v.y;
  hv[2] = r1.z * rstd * w1v.z; hv[3] = r1.w * rstd * w1v.w;
  hv[4] = r2.x * rstd * w2v.x; hv[5] = r2.y * rstd * w2v.y;
  hv[6] = r2.z * rstd * w2v.z; hv[7] = r2.w * rstd * w2v.w;
  ushort4 o1, o2, l1, l2;
  u16 h;
  h = f2b(hv[0]); o1.x = h; l1.x = f2b(hv[0] - b2f(h));
  h = f2b(hv[1]); o1.y = h; l1.y = f2b(hv[1] - b2f(h));
  h = f2b(hv[2]); o1.z = h; l1.z = f2b(hv[2] - b2f(h));
  h = f2b(hv[3]); o1.w = h; l1.w = f2b(hv[3] - b2f(h));
  h = f2b(hv[4]); o2.x = h; l2.x = f2b(hv[4] - b2f(h));
  h = f2b(hv[5]); o2.y = h; l2.y = f2b(hv[5] - b2f(h));
  h = f2b(hv[6]); o2.z = h; l2.z = f2b(hv[6] - b2f(h));
  h = f2b(hv[7]); o2.w = h; l2.w = f2b(hv[7] - b2f(h));
  *(ushort4*)(hb + base + tid * 4) = o1;
  *(ushort4*)(hb + base + 1024 + tid * 4) = o2;
  *(ushort4*)(hblo + base + tid * 4) = l1;
  *(ushort4*)(hblo + base + 1024 + tid * 4) = l2;
}

// ---------------- transpose f32 [K][N] -> bf16 [N][K], 64x64 tiles ----------------
__global__ void k_transpose64(const float* __restrict__ src, u16* __restrict__ dst,
                              int K, int N) {
  size_t zo = (size_t)blockIdx.z * K * N;
  src += zo; dst += zo;
  __shared__ float tl[64][65];
  const int t = threadIdx.x;
  const int k0 = blockIdx.x * 64, n0 = blockIdx.y * 64;
  int r = t >> 4, c = (t & 15) * 4;
#pragma unroll
  for (int u = 0; u < 4; u++) {
    float4 v = *(const float4*)(src + (size_t)(k0 + r + u * 16) * N + n0 + c);
    tl[r + u * 16][c] = v.x; tl[r + u * 16][c + 1] = v.y;
    tl[r + u * 16][c + 2] = v.z; tl[r + u * 16][c + 3] = v.w;
  }
  __syncthreads();
  int n = t >> 2, kc = (t & 3) * 16;
  __align__(16) u16 tmp[16];
#pragma unroll
  for (int i = 0; i < 16; i++) tmp[i] = f2b(tl[kc + i][n]);
  uint4* dp = (uint4*)(dst + (size_t)(n0 + n) * K + k0 + kc);
  dp[0] = ((uint4*)tmp)[0];
  dp[1] = ((uint4*)tmp)[1];
}

// ---------------- transpose f32 [K][N] -> bf16 hi/lo [N][K], 64x64 tiles ----------------
__global__ void k_transpose2_64(const float* __restrict__ src, u16* __restrict__ dhi,
                                u16* __restrict__ dlo, int K, int N) {
  __shared__ float tl[64][65];
  const int t = threadIdx.x;
  const int k0 = blockIdx.x * 64, n0 = blockIdx.y * 64;
  int r = t >> 4, c = (t & 15) * 4;
#pragma unroll
  for (int u = 0; u < 4; u++) {
    float4 v = *(const float4*)(src + (size_t)(k0 + r + u * 16) * N + n0 + c);
    tl[r + u * 16][c] = v.x; tl[r + u * 16][c + 1] = v.y;
    tl[r + u * 16][c + 2] = v.z; tl[r + u * 16][c + 3] = v.w;
  }
  __syncthreads();
  int n = t >> 2, kc = (t & 3) * 16;
  __align__(16) u16 th[16], tlo[16];
#pragma unroll
  for (int i = 0; i < 16; i++) {
    float x = tl[kc + i][n];
    u16 hx = f2b(x);
    th[i] = hx; tlo[i] = f2b(x - b2f(hx));
  }
  uint4* dph = (uint4*)(dhi + (size_t)(n0 + n) * K + k0 + kc);
  dph[0] = ((uint4*)th)[0]; dph[1] = ((uint4*)th)[1];
  uint4* dpl = (uint4*)(dlo + (size_t)(n0 + n) * K + k0 + kc);
  dpl[0] = ((uint4*)tlo)[0]; dpl[1] = ((uint4*)tlo)[1];
}

// ---------------- split-bf16 GEMM: C[M,3072] = (Ahi+Alo)[M,2048] * (Bhi+Blo)^T ----------------
__launch_bounds__(256, 2)
__global__ void gemm_qkv(const u16* __restrict__ Ahi, const u16* __restrict__ Alo,
                         const u16* __restrict__ Bhi, const u16* __restrict__ Blo,
                         float* __restrict__ C) {
  __shared__ __align__(16) u16 Ah[2][128 * 32];
  __shared__ __align__(16) u16 Al[2][128 * 32];
  __shared__ __align__(16) u16 Bh[2][128 * 32];
  __shared__ __align__(16) u16 Bl[2][128 * 32];
  const int tid = threadIdx.x;
  const int wid = tid >> 6, lane = tid & 63, lr = lane & 15, lg = lane >> 4;
  const int m0 = blockIdx.x * 128, n0 = blockIdx.y * 128;
  const int wm = (wid >> 1) * 64, wn = (wid & 1) * 64;
  const int c0 = tid, c1 = tid + 256;
  // source-side swizzle (slot ^ (row>>1)&3) so LDS is linear for gll16 but
  // fragment reads are bank-conflict-free
  const int ss0 = ((c0 & 3) ^ ((c0 >> 3) & 3)) * 8;
  const int ss1 = ((c1 & 3) ^ ((c1 >> 3) & 3)) * 8;
  const int fs = (lg ^ ((lr >> 1) & 3)) * 8;   // fragment-read swizzled slot
  const size_t ao0 = (size_t)(m0 + (c0 >> 2)) * 2048 + ss0;
  const size_t ao1 = (size_t)(m0 + (c1 >> 2)) * 2048 + ss1;
  const size_t bo0 = (size_t)(n0 + (c0 >> 2)) * 2048 + ss0;
  const size_t bo1 = (size_t)(n0 + (c1 >> 2)) * 2048 + ss1;
  f32x4 zv = {0.f, 0.f, 0.f, 0.f};
  f32x4 acc[4][4];
#pragma unroll
  for (int i = 0; i < 4; i++)
#pragma unroll
    for (int j = 0; j < 4; j++) acc[i][j] = zv;
  const int NT = 2048 >> 5;
  gll16(Ahi + ao0, &Ah[0][c0 * 8]); gll16(Ahi + ao1, &Ah[0][c1 * 8]);
  gll16(Alo + ao0, &Al[0][c0 * 8]); gll16(Alo + ao1, &Al[0][c1 * 8]);
  gll16(Bhi + bo0, &Bh[0][c0 * 8]); gll16(Bhi + bo1, &Bh[0][c1 * 8]);
  gll16(Blo + bo0, &Bl[0][c0 * 8]); gll16(Blo + bo1, &Bl[0][c1 * 8]);
  int cur = 0;
  for (int t = 0; t < NT; ++t) {
    __syncthreads();
    if (t + 1 < NT) {
      int ko = (t + 1) << 5;
      gll16(Ahi + ao0 + ko, &Ah[cur ^ 1][c0 * 8]); gll16(Ahi + ao1 + ko, &Ah[cur ^ 1][c1 * 8]);
      gll16(Alo + ao0 + ko, &Al[cur ^ 1][c0 * 8]); gll16(Alo + ao1 + ko, &Al[cur ^ 1][c1 * 8]);
      gll16(Bhi + bo0 + ko, &Bh[cur ^ 1][c0 * 8]); gll16(Bhi + bo1 + ko, &Bh[cur ^ 1][c1 * 8]);
      gll16(Blo + bo0 + ko, &Bl[cur ^ 1][c0 * 8]); gll16(Blo + bo1 + ko, &Bl[cur ^ 1][c1 * 8]);
    }
    bf16x8 ah[4], al[4], bh[4], bl[4];
#pragma unroll
    for (int i = 0; i < 4; i++) {
      ah[i] = *(const bf16x8*)&Ah[cur][(wm + i * 16 + lr) * 32 + fs];
      al[i] = *(const bf16x8*)&Al[cur][(wm + i * 16 + lr) * 32 + fs];
    }
#pragma unroll
    for (int j = 0; j < 4; j++) {
      bh[j] = *(const bf16x8*)&Bh[cur][(wn + j * 16 + lr) * 32 + fs];
      bl[j] = *(const bf16x8*)&Bl[cur][(wn + j * 16 + lr) * 32 + fs];
    }
#pragma unroll
    for (int i = 0; i < 4; i++)
#pragma unroll
      for (int j = 0; j < 4; j++) {
        acc[i][j] = __builtin_amdgcn_mfma_f32_16x16x32_bf16(ah[i], bh[j], acc[i][j], 0, 0, 0);
        acc[i][j] = __builtin_amdgcn_mfma_f32_16x16x32_bf16(ah[i], bl[j], acc[i][j], 0, 0, 0);
        acc[i][j] = __builtin_amdgcn_mfma_f32_16x16x32_bf16(al[i], bh[j], acc[i][j], 0, 0, 0);
      }
    cur ^= 1;
  }
#pragma unroll
  for (int i = 0; i < 4; i++) {
    const int row = m0 + wm + i * 16 + lg * 4;
#pragma unroll
    for (int j = 0; j < 4; j++) {
      const int col = n0 + wn + j * 16 + lr;
#pragma unroll
      for (int r = 0; r < 4; r++)
        C[(size_t)(row + r) * 3072 + col] = acc[i][j][r];
    }
  }
}

// ---------------- GEMM C[M,N] = A[M,K]bf16 * BT[N,K]bf16 (+residual) ----------------
template <int MODE>
__launch_bounds__(256, 3)
__global__ void gemm_bt(const u16* __restrict__ A, const u16* __restrict__ BT,
                        float* __restrict__ C, const float* __restrict__ addf,
                        int N, int K) {
  __shared__ __align__(16) u16 Albuf[2][128 * 32];
  __shared__ __align__(16) u16 Blbuf[2][128 * 32];
  const int tid = threadIdx.x;
  const int wid = tid >> 6, lane = tid & 63, lr = lane & 15, lg = lane >> 4;
  const int m0 = blockIdx.x * 128, n0 = blockIdx.y * 128;
  const int wm = (wid >> 1) * 64, wn = (wid & 1) * 64;
  const int c0 = tid, c1 = tid + 256;
  const int ss0 = ((c0 & 3) ^ ((c0 >> 3) & 3)) * 8;
  const int ss1 = ((c1 & 3) ^ ((c1 >> 3) & 3)) * 8;
  const int fs = (lg ^ ((lr >> 1) & 3)) * 8;
  const u16* a0 = A + (size_t)(m0 + (c0 >> 2)) * K + ss0;
  const u16* a1 = A + (size_t)(m0 + (c1 >> 2)) * K + ss1;
  const u16* b0 = BT + (size_t)(n0 + (c0 >> 2)) * K + ss0;
  const u16* b1 = BT + (size_t)(n0 + (c1 >> 2)) * K + ss1;
  f32x4 zv = {0.f, 0.f, 0.f, 0.f};
  f32x4 acc[4][4];
#pragma unroll
  for (int i = 0; i < 4; i++)
#pragma unroll
    for (int j = 0; j < 4; j++) acc[i][j] = zv;
  const int NT = K >> 5;
  gll16(a0, &Albuf[0][c0 * 8]); gll16(a1, &Albuf[0][c1 * 8]);
  gll16(b0, &Blbuf[0][c0 * 8]); gll16(b1, &Blbuf[0][c1 * 8]);
  int cur = 0;
  for (int t = 0; t < NT; ++t) {
    __syncthreads();
    if (t + 1 < NT) {
      int ko = (t + 1) << 5;
      gll16(a0 + ko, &Albuf[cur ^ 1][c0 * 8]); gll16(a1 + ko, &Albuf[cur ^ 1][c1 * 8]);
      gll16(b0 + ko, &Blbuf[cur ^ 1][c0 * 8]); gll16(b1 + ko, &Blbuf[cur ^ 1][c1 * 8]);
    }
    bf16x8 af[4], bf[4];
#pragma unroll
    for (int i = 0; i < 4; i++) af[i] = *(const bf16x8*)&Albuf[cur][(wm + i * 16 + lr) * 32 + fs];
#pragma unroll
    for (int j = 0; j < 4; j++) bf[j] = *(const bf16x8*)&Blbuf[cur][(wn + j * 16 + lr) * 32 + fs];
#pragma unroll
    for (int i = 0; i < 4; i++)
#pragma unroll
      for (int j = 0; j < 4; j++)
        acc[i][j] = __builtin_amdgcn_mfma_f32_16x16x32_bf16(af[i], bf[j], acc[i][j], 0, 0, 0);
    cur ^= 1;
  }
#pragma unroll
  for (int i = 0; i < 4; i++) {
    const int row = m0 + wm + i * 16 + lg * 4;
#pragma unroll
    for (int j = 0; j < 4; j++) {
      const int col = n0 + wn + j * 16 + lr;
#pragma unroll
      for (int r = 0; r < 4; r++) {
        float v = acc[i][j][r];
        if (MODE == 1) v += addf[(size_t)(row + r) * N + col];
        C[(size_t)(row + r) * N + col] = v;
      }
    }
  }
}

// ---------------- RoPE + bf16 hi/lo pack of q/k, bf16 v ----------------
__global__ void k_rope(const int* __restrict__ pos, const float* __restrict__ qkvf,
                       u16* __restrict__ qhi, u16* __restrict__ qlo,
                       u16* __restrict__ khi, u16* __restrict__ klo,
                       u16* __restrict__ vb) {
  __shared__ float invtab[64];
  const int t = blockIdx.x, tid = threadIdx.x;
  if (tid < 64) invtab[tid] = 1.0f / (float)pow(1.0e6, (double)tid / 64.0);
  __syncthreads();
  const float p = (float)pos[t];
  const float* src = qkvf + (size_t)t * 3072;
#pragma unroll
  for (int it = 0; it < 4; ++it) {
    int idx = tid + it * 256;
    int head = idx >> 6, i = idx & 63;
    float ang = p * invtab[i];
    float cc, ssn;
    sincosf(ang, &ssn, &cc);
    float x1 = src[head * 128 + i], x2 = src[head * 128 + i + 64];
    float y1 = x1 * cc - x2 * ssn;
    float y2 = x2 * cc + x1 * ssn;
    u16 h1 = f2b(y1), h2 = f2b(y2);
    size_t o1 = (size_t)t * 2048 + head * 128 + i;
    qhi[o1] = h1;      qlo[o1] = f2b(y1 - b2f(h1));
    qhi[o1 + 64] = h2; qlo[o1 + 64] = f2b(y2 - b2f(h2));
  }
  {
    int head = tid >> 6, i = tid & 63;
    float ang = p * invtab[i];
    float cc, ssn;
    sincosf(ang, &ssn, &cc);
    float x1 = src[2048 + head * 128 + i], x2 = src[2048 + head * 128 + i + 64];
    float y1 = x1 * cc - x2 * ssn;
    float y2 = x2 * cc + x1 * ssn;
    u16 h1 = f2b(y1), h2 = f2b(y2);
    size_t o1 = (size_t)t * 512 + head * 128 + i;
    khi[o1] = h1;      klo[o1] = f2b(y1 - b2f(h1));
    khi[o1 + 64] = h2; klo[o1 + 64] = f2b(y2 - b2f(h2));
  }
#pragma unroll
  for (int u = 0; u < 2; ++u) {
    int ccol = tid + u * 256;
    vb[(size_t)t * 512 + ccol] = f2b(src[2560 + ccol]);
  }
}

// ---------------- tiny f32 helpers for the accurate gate path ----------------
__global__ void k_G(const float* __restrict__ ln2w, const float* __restrict__ gw,
                    float* __restrict__ G) {
  int i = blockIdx.x * 256 + threadIdx.x;   // 2048*8
  G[i] = ln2w[i >> 3] * gw[i];
}
__global__ void k_WG(const float* __restrict__ wo, const float* __restrict__ G,
                     float* __restrict__ WG) {
  int i = blockIdx.x * 256 + threadIdx.x;   // 2048*8
  int r = i >> 3, e = i & 7;
  const float* wr_ = wo + (size_t)r * 2048;
  float s0 = 0, s1 = 0, s2 = 0, s3 = 0;
  for (int c = 0; c < 2048; c += 4) {
    s0 += wr_[c] * G[c * 8 + e];
    s1 += wr_[c + 1] * G[(c + 1) * 8 + e];
    s2 += wr_[c + 2] * G[(c + 2) * 8 + e];
    s3 += wr_[c + 3] * G[(c + 3) * 8 + e];
  }
  WG[i] = (s0 + s1) + (s2 + s3);
}
__global__ void k_resG(const float* __restrict__ resf, const float* __restrict__ G,
                       float* __restrict__ resG) {
  int i = blockIdx.x * 256 + threadIdx.x;   // 2048*8
  int t = i >> 3, e = i & 7;
  const float* rr = resf + (size_t)t * 2048;
  float s0 = 0, s1 = 0, s2 = 0, s3 = 0;
  for (int c = 0; c < 2048; c += 4) {
    s0 += rr[c] * G[c * 8 + e];
    s1 += rr[c + 1] * G[(c + 1) * 8 + e];
    s2 += rr[c + 2] * G[(c + 2) * 8 + e];
    s3 += rr[c + 3] * G[(c + 3) * 8 + e];
  }
  resG[i] = (s0 + s1) + (s2 + s3);
}
__global__ void k_VG(const float* __restrict__ qkvf, const float* __restrict__ WG,
                     float* __restrict__ VG) {
  int i = blockIdx.x * 256 + threadIdx.x;   // 16*2048*8
  int e = i & 7, t = (i >> 3) & 2047, h = i >> 14;
  const float* vr = qkvf + (size_t)t * 3072 + 2560 + (h >> 2) * 128;
  const float* wgr = WG + (size_t)(h * 128) * 8 + e;
  float s = 0;
#pragma unroll 4
  for (int d = 0; d < 128; d++) s += vr[d] * wgr[d * 8];
  VG[i] = s;   // layout [h][t][e]
}

// ---------------- merged flash attention: accurate S (3-term) shared by
// PV (bf16 main path) and the p@VG gate path. Q direct to registers. ----------------
__launch_bounds__(256, 2)
__global__ void k_attn2(const u16* __restrict__ qh, const u16* __restrict__ qlo,
                        const u16* __restrict__ kh, const u16* __restrict__ klo,
                        const u16* __restrict__ vb, const float* __restrict__ vg,
                        u16* __restrict__ attnb, float* __restrict__ pvgp) {
  __shared__ __align__(16) u16 Kh[64 * 128];
  __shared__ __align__(16) u16 Kl[64 * 128];
  __shared__ __align__(16) u16 VTl[128 * 64];
  __shared__ __align__(16) u16 Pl[4][16 * 72];
  __shared__ float VGt[64][9];
  const int tid = threadIdx.x, wid = tid >> 6, lane = tid & 63, lr = lane & 15, lg = lane >> 4;
  const int h = blockIdx.y, hk = h >> 2, q0 = blockIdx.x * 64, wr = wid * 16;
  float m_[4], l_[4], avg[4][8];
  f32x4 zv = {0.f, 0.f, 0.f, 0.f};
  f32x4 accO[8];
#pragma unroll
  for (int r = 0; r < 4; r++) {
    m_[r] = -3e38f; l_[r] = 0.f;
#pragma unroll
    for (int e = 0; e < 8; e++) avg[r][e] = 0.f;
  }
#pragma unroll
  for (int d = 0; d < 8; d++) accO[d] = zv;
  // Q fragments straight from global (once per block)
  bf16x8 aqh[4], aql[4];
  {
    const size_t qb = (size_t)(q0 + wr + lr) * 2048 + h * 128 + lg * 8;
#pragma unroll
    for (int kk = 0; kk < 4; kk++) {
      aqh[kk] = *(const bf16x8*)(qh + qb + kk * 32);
      aql[kk] = *(const bf16x8*)(qlo + qb + kk * 32);
    }
  }
  const int nk = blockIdx.x + 1;
  for (int kt = 0; kt < nk; ++kt) {
    const int s0 = kt * 64;
    __syncthreads();
#pragma unroll
    for (int i = 0; i < 4; i++) {
      int c = tid + i * 256;
      int s = c >> 4, b = (c & 15) * 8;
      size_t go = (size_t)(s0 + s) * 512 + hk * 128 + (b ^ ((s & 7) << 3));
      gll16(kh + go, &Kh[c * 8]);
      gll16(klo + go, &Kl[c * 8]);
    }
    {
      int s = tid >> 2;
      const u16* vsrc = vb + (size_t)(s0 + s) * 512 + hk * 128 + (tid & 3) * 32;
#pragma unroll
      for (int u = 0; u < 4; u++) {
        uint4 wv = *(const uint4*)(vsrc + u * 8);
        const u16* tp = (const u16*)&wv;
        int d0b = (tid & 3) * 32 + u * 8;
        int scol = s ^ (((d0b >> 3) & 7) << 3);
#pragma unroll
        for (int ii = 0; ii < 8; ii++) VTl[(d0b + ii) * 64 + scol] = tp[ii];
      }
    }
#pragma unroll
    for (int it = 0; it < 2; ++it) {
      int idx = tid + it * 256;
      int ss = idx >> 3, ee = idx & 7;
      VGt[ss][ee] = vg[((size_t)h * 2048 + s0 + ss) * 8 + ee];
    }
    __syncthreads();
    f32x4 accS[4];
#pragma unroll
    for (int ct = 0; ct < 4; ct++) accS[ct] = zv;
#pragma unroll
    for (int kk = 0; kk < 4; kk++) {
#pragma unroll
      for (int ct = 0; ct < 4; ct++) {
        int off = (ct * 16 + lr) * 128 + ((kk * 32 + lg * 8) ^ ((lr & 7) << 3));
        bf16x8 bh = *(const bf16x8*)&Kh[off];
        bf16x8 bl = *(const bf16x8*)&Kl[off];
        accS[ct] = __builtin_amdgcn_mfma_f32_16x16x32_bf16(aqh[kk], bh, accS[ct], 0, 0, 0);
        accS[ct] = __builtin_amdgcn_mfma_f32_16x16x32_bf16(aqh[kk], bl, accS[ct], 0, 0, 0);
        accS[ct] = __builtin_amdgcn_mfma_f32_16x16x32_bf16(aql[kk], bh, accS[ct], 0, 0, 0);
      }
    }
    const bool diag = (kt == blockIdx.x);
    float alpha[4];
#pragma unroll
    for (int r = 0; r < 4; r++) {
      float sv[4];
      float mx = -3e38f;
#pragma unroll
      for (int ct = 0; ct < 4; ct++) {
        float sc = accS[ct][r] * 0.08838834764831845f;
        if (diag) {
          int col = ct * 16 + lr;
          int row = wr + lg * 4 + r;
          if (col > row) sc = -3e38f;
        }
        sv[ct] = sc; mx = fmaxf(mx, sc);
      }
#pragma unroll
      for (int m2 = 1; m2 < 16; m2 <<= 1) mx = fmaxf(mx, __shfl_xor(mx, m2));
      float mnew = fmaxf(m_[r], mx);
      float a = expf(m_[r] - mnew);
      float pv[4];
      float rs = 0.f;
#pragma unroll
      for (int ct = 0; ct < 4; ct++) { pv[ct] = expf(sv[ct] - mnew); rs += pv[ct]; }
#pragma unroll
      for (int m2 = 1; m2 < 16; m2 <<= 1) rs += __shfl_xor(rs, m2);
      l_[r] = l_[r] * a + rs;
      m_[r] = mnew;
      alpha[r] = a;
#pragma unroll
      for (int e = 0; e < 8; e++) avg[r][e] *= a;
#pragma unroll
      for (int ct = 0; ct < 4; ct++) {
        int vrow = ct * 16 + lr;
        Pl[wid][(lg * 4 + r) * 72 + ct * 16 + lr] = f2b(pv[ct]);
#pragma unroll
        for (int e = 0; e < 8; e++) avg[r][e] += pv[ct] * VGt[vrow][e];
      }
    }
#pragma unroll
    for (int d = 0; d < 8; d++)
#pragma unroll
      for (int r = 0; r < 4; r++) accO[d][r] *= alpha[r];
    __syncthreads();
#pragma unroll
    for (int ks = 0; ks < 2; ks++) {
      bf16x8 ap = *(const bf16x8*)&Pl[wid][lr * 72 + ks * 32 + lg * 8];
#pragma unroll
      for (int d0 = 0; d0 < 8; d0++) {
        int d = d0 * 16 + lr;
        int scol = (ks * 32 + lg * 8) ^ (((d >> 3) & 7) << 3);
        bf16x8 bv = *(const bf16x8*)&VTl[d * 64 + scol];
        accO[d0] = __builtin_amdgcn_mfma_f32_16x16x32_bf16(ap, bv, accO[d0], 0, 0, 0);
      }
    }
  }
#pragma unroll
  for (int d0 = 0; d0 < 8; d0++)
#pragma unroll
    for (int r = 0; r < 4; r++) {
      float v = accO[d0][r] / l_[r];
      attnb[(size_t)(q0 + wr + lg * 4 + r) * 2048 + h * 128 + d0 * 16 + lr] = f2b(v);
    }
#pragma unroll
  for (int m2 = 1; m2 < 16; m2 <<= 1)
#pragma unroll
    for (int r = 0; r < 4; r++)
#pragma unroll
      for (int e = 0; e < 8; e++) avg[r][e] += __shfl_xor(avg[r][e], m2);
#pragma unroll
  for (int r = 0; r < 4; r++) {
    int t = q0 + wr + lg * 4 + r;
    float inv = 1.f / l_[r];
#pragma unroll
    for (int e = 0; e < 8; e++)
      if (lr == e) pvgp[((size_t)h * 2048 + t) * 8 + e] = avg[r][e] * inv;
  }
}

// ---------------- RMSNorm(ln2) + accurate-logit gate + top2 routing ----------------
__global__ void k_ln2gate(const float* __restrict__ res2, const float* __restrict__ w,
                          const float* __restrict__ resG, const float* __restrict__ pvgp,
                          u16* __restrict__ h2b,
                          int* __restrict__ cnt, int* __restrict__ tok,
                          float* __restrict__ wgt, int* __restrict__ jid) {
  const int t = blockIdx.x, tid = threadIdx.x, lane = tid & 63, wid = tid >> 6;
  __shared__ float red[4];
  const size_t base = (size_t)t * Hh;
  float4 r1 = *(const float4*)(res2 + base + tid * 4);
  float4 r2 = *(const float4*)(res2 + base + 1024 + tid * 4);
  float ss = r1.x*r1.x + r1.y*r1.y + r1.z*r1.z + r1.w*r1.w
           + r2.x*r2.x + r2.y*r2.y + r2.z*r2.z + r2.w*r2.w;
#pragma unroll
  for (int m = 1; m < 64; m <<= 1) ss += __shfl_xor(ss, m);
  if (lane == 0) red[wid] = ss;
  __syncthreads();
  float tot = red[0] + red[1] + red[2] + red[3];
  float rstd = rsqrtf(tot * (1.f / Hh) + 1e-5f);
  float4 w1v = *(const float4*)(w + tid * 4);
  float4 w2v = *(const float4*)(w + 1024 + tid * 4);
  ushort4 o1, o2;
  o1.x = f2b(r1.x * rstd * w1v.x); o1.y = f2b(r1.y * rstd * w1v.y);
  o1.z = f2b(r1.z * rstd * w1v.z); o1.w = f2b(r1.w * rstd * w1v.w);
  o2.x = f2b(r2.x * rstd * w2v.x); o2.y = f2b(r2.y * rstd * w2v.y);
  o2.z = f2b(r2.z * rstd * w2v.z); o2.w = f2b(r2.w * rstd * w2v.w);
  *(ushort4*)(h2b + base + tid * 4) = o1;
  *(ushort4*)(h2b + base + 1024 + tid * 4) = o2;
  if (tid == 0) {
    float lg8[8];
#pragma unroll
    for (int e = 0; e < 8; e++) {
      float s = resG[t * 8 + e];
      for (int hh = 0; hh < 16; hh++) s += pvgp[((size_t)hh * 2048 + t) * 8 + e];
      lg8[e] = s * rstd;
    }
    float mx = lg8[0];
#pragma unroll
    for (int e = 1; e < 8; e++) mx = fmaxf(mx, lg8[e]);
    float ex[8];
#pragma unroll
    for (int e = 0; e < 8; e++) ex[e] = expf(lg8[e] - mx);
    int i1 = 0; float v1 = ex[0];
#pragma unroll
    for (int e = 1; e < 8; e++) if (ex[e] > v1) { v1 = ex[e]; i1 = e; }
    int i2 = -1; float v2 = -1.f;
#pragma unroll
    for (int e = 0; e < 8; e++) if (e != i1 && ex[e] > v2) { v2 = ex[e]; i2 = e; }
    float inv = 1.f / (v1 + v2);
    int s1 = atomicAdd(&cnt[i1], 1);
    tok[i1 * 2048 + s1] = t; wgt[i1 * 2048 + s1] = v1 * inv; jid[i1 * 2048 + s1] = 0;
    int s2 = atomicAdd(&cnt[i2], 1);
    tok[i2 * 2048 + s2] = t; wgt[i2 * 2048 + s2] = v2 * inv; jid[i2 * 2048 + s2] = 1;
  }
}

// ---------------- MoE GEMM1, split into two single-B passes ----------------
// PHASE 0: x1 = h2 @ w1[e]          (f32 to x1 scratch)
// PHASE 1: acc = h2 @ w3[e]; g = silu(x1) * acc -> gbuf (bf16)
// Rationale: the fused dual-B version needed 128 acc regs + ~84 arch ≈ 212/wave
// -> only 2 waves/SIMD (measured Occupancy 25%). Single-B is ~148/wave -> 3
// waves/SIMD, and halves the live weight set per dispatch (134MB, L3-resident).
template <int PHASE>
__launch_bounds__(256, 3)
__global__ void gemm_m13(const u16* __restrict__ h2b, const u16* __restrict__ wT,
                         u16* __restrict__ gbuf, float* __restrict__ x1,
                         const int* __restrict__ cnt, const int* __restrict__ tok) {
  const int e = blockIdx.z;
  const int cnt_e = cnt[e];
  const int m0 = blockIdx.y * 128;
  if (m0 >= cnt_e) return;
  int gb = 0;
#pragma unroll
  for (int i = 0; i < 8; i++) if (i < e) gb += cnt[i];
  __shared__ __align__(16) u16 Al[2][128 * 32];
  __shared__ __align__(16) u16 Bl[2][128 * 32];
  const int tid = threadIdx.x;
  const int wid = tid >> 6, lane = tid & 63, lr = lane & 15, lg = lane >> 4;
  const int n0 = blockIdx.x * 128;
  const int wm = (wid >> 1) * 64, wn = (wid & 1) * 64;
  const int c0 = tid, c1 = tid + 256;
  const int ss0 = ((c0 & 3) ^ ((c0 >> 3) & 3)) * 8;
  const int ss1 = ((c1 & 3) ^ ((c1 >> 3) & 3)) * 8;
  const int fs = (lg ^ ((lr >> 1) & 3)) * 8;
  int r0 = m0 + (c0 >> 2); if (r0 > cnt_e - 1) r0 = cnt_e - 1;
  int r1 = m0 + (c1 >> 2); if (r1 > cnt_e - 1) r1 = cnt_e - 1;
  const int tk0 = tok[e * 2048 + r0], tk1 = tok[e * 2048 + r1];
  const u16* a0 = h2b + (size_t)tk0 * 2048 + ss0;
  const u16* a1 = h2b + (size_t)tk1 * 2048 + ss1;
  const u16* b0 = wT + (size_t)e * DFFd * 2048 + (size_t)(n0 + (c0 >> 2)) * 2048 + ss0;
  const u16* b1 = wT + (size_t)e * DFFd * 2048 + (size_t)(n0 + (c1 >> 2)) * 2048 + ss1;
  f32x4 zv = {0.f, 0.f, 0.f, 0.f};
  f32x4 acc[4][4];
#pragma unroll
  for (int i = 0; i < 4; i++)
#pragma unroll
    for (int j = 0; j < 4; j++) acc[i][j] = zv;
  const int NT = 2048 >> 5;
  gll16(a0, &Al[0][c0 * 8]); gll16(a1, &Al[0][c1 * 8]);
  gll16(b0, &Bl[0][c0 * 8]); gll16(b1, &Bl[0][c1 * 8]);
  int cur = 0;
  for (int t = 0; t < NT; ++t) {
    __syncthreads();
    if (t + 1 < NT) {
      int ko = (t + 1) << 5;
      gll16(a0 + ko, &Al[cur ^ 1][c0 * 8]); gll16(a1 + ko, &Al[cur ^ 1][c1 * 8]);
      gll16(b0 + ko, &Bl[cur ^ 1][c0 * 8]); gll16(b1 + ko, &Bl[cur ^ 1][c1 * 8]);
    }
    bf16x8 af[4], bf[4];
#pragma unroll
    for (int i = 0; i < 4; i++) af[i] = *(const bf16x8*)&Al[cur][(wm + i * 16 + lr) * 32 + fs];
#pragma unroll
    for (int j = 0; j < 4; j++) bf[j] = *(const bf16x8*)&Bl[cur][(wn + j * 16 + lr) * 32 + fs];
#pragma unroll
    for (int i = 0; i < 4; i++)
#pragma unroll
      for (int j = 0; j < 4; j++)
        acc[i][j] = __builtin_amdgcn_mfma_f32_16x16x32_bf16(af[i], bf[j], acc[i][j], 0, 0, 0);
    cur ^= 1;
  }
#pragma unroll
  for (int i = 0; i < 4; i++) {
    const int slotb = m0 + wm + i * 16 + lg * 4;
#pragma unroll
    for (int j = 0; j < 4; j++) {
      const int col = n0 + wn + j * 16 + lr;
#pragma unroll
      for (int r = 0; r < 4; r++) {
        int slot = slotb + r;
        if (slot < cnt_e) {
          size_t o = (size_t)(gb + slot) * DFFd + col;
          if (PHASE == 0) {
            x1[o] = acc[i][j][r];
          } else {
            float xv = x1[o];
            float g = xv / (1.f + __expf(-xv)) * acc[i][j][r];
            gbuf[o] = f2b(g);
          }
        }
      }
    }
  }
}

// ---------------- MoE GEMM2: out_j[token] = w * (g @ w2) ----------------
__launch_bounds__(256, 3)
__global__ void gemm2k(const u16* __restrict__ gbuf, const u16* __restrict__ w2T,
                       float* __restrict__ outk, const int* __restrict__ cnt,
                       const int* __restrict__ tok, const float* __restrict__ wgt,
                       const int* __restrict__ jid) {
  const int e = blockIdx.z;
  const int cnt_e = cnt[e];
  const int m0 = blockIdx.y * 128;
  if (m0 >= cnt_e) return;
  int gb = 0;
#pragma unroll
  for (int i = 0; i < 8; i++) if (i < e) gb += cnt[i];
  __shared__ __align__(16) u16 Al[2][128 * 32];
  __shared__ __align__(16) u16 Bl[2][128 * 32];
  const int tid = threadIdx.x;
  const int wid = tid >> 6, lane = tid & 63, lr = lane & 15, lg = lane >> 4;
  const int n0 = blockIdx.x * 128;
  const int wm = (wid >> 1) * 64, wn = (wid & 1) * 64;
  const int c0 = tid, c1 = tid + 256;
  const int ss0 = ((c0 & 3) ^ ((c0 >> 3) & 3)) * 8;
  const int ss1 = ((c1 & 3) ^ ((c1 >> 3) & 3)) * 8;
  const int fs = (lg ^ ((lr >> 1) & 3)) * 8;
  const u16* A = gbuf + (size_t)gb * DFFd;
  const u16* a0 = A + (size_t)(m0 + (c0 >> 2)) * DFFd + ss0;
  const u16* a1 = A + (size_t)(m0 + (c1 >> 2)) * DFFd + ss1;
  const u16* b0 = w2T + (size_t)e * 2048 * DFFd + (size_t)(n0 + (c0 >> 2)) * DFFd + ss0;
  const u16* b1 = w2T + (size_t)e * 2048 * DFFd + (size_t)(n0 + (c1 >> 2)) * DFFd + ss1;
  f32x4 zv = {0.f, 0.f, 0.f, 0.f};
  f32x4 acc[4][4];
#pragma unroll
  for (int i = 0; i < 4; i++)
#pragma unroll
    for (int j = 0; j < 4; j++) acc[i][j] = zv;
  const int NT = DFFd >> 5;
  gll16(a0, &Al[0][c0 * 8]); gll16(a1, &Al[0][c1 * 8]);
  gll16(b0, &Bl[0][c0 * 8]); gll16(b1, &Bl[0][c1 * 8]);
  int cur = 0;
  for (int t = 0; t < NT; ++t) {
    __syncthreads();
    if (t + 1 < NT) {
      int ko = (t + 1) << 5;
      gll16(a0 + ko, &Al[cur ^ 1][c0 * 8]); gll16(a1 + ko, &Al[cur ^ 1][c1 * 8]);
      gll16(b0 + ko, &Bl[cur ^ 1][c0 * 8]); gll16(b1 + ko, &Bl[cur ^ 1][c1 * 8]);
    }
    bf16x8 af[4], bf[4];
#pragma unroll
    for (int i = 0; i < 4; i++) af[i] = *(const bf16x8*)&Al[cur][(wm + i * 16 + lr) * 32 + fs];
#pragma unroll
    for (int j = 0; j < 4; j++) bf[j] = *(const bf16x8*)&Bl[cur][(wn + j * 16 + lr) * 32 + fs];
#pragma unroll
    for (int i = 0; i < 4; i++)
#pragma unroll
      for (int j = 0; j < 4; j++)
        acc[i][j] = __builtin_amdgcn_mfma_f32_16x16x32_bf16(af[i], bf[j], acc[i][j], 0, 0, 0);
    cur ^= 1;
  }
#pragma unroll
  for (int i = 0; i < 4; i++) {
    const int slotb = m0 + wm + i * 16 + lg * 4;
#pragma unroll
    for (int r = 0; r < 4; r++) {
      int slot = slotb + r;
      if (slot < cnt_e) {
        int tkn = tok[e * 2048 + slot];
        float wv = wgt[e * 2048 + slot];
        int jj = jid[e * 2048 + slot];
        float* orow = outk + (size_t)jj * ((size_t)Tt * Hh) + (size_t)tkn * Hh;
#pragma unroll
        for (int j = 0; j < 4; j++) {
          const int col = n0 + wn + j * 16 + lr;
          orow[col] = wv * acc[i][j][r];
        }
      }
    }
  }
}

__global__ void k_zero(int* cnt) { if (threadIdx.x < 8) cnt[threadIdx.x] = 0; }

__global__ void k_combine(const float* __restrict__ outk, float* __restrict__ dout) {
  size_t i = ((size_t)blockIdx.x * 256 + threadIdx.x) * 4;
  float4 a = *(const float4*)(outk + i);
  float4 b = *(const float4*)(outk + (size_t)Tt * Hh + i);
  float4 o = {a.x + b.x, a.y + b.y, a.z + b.z, a.w + b.w};
  *(float4*)(dout + i) = o;
}

extern "C" void kernel_launch(void* const* d_in, const int* in_sizes, int n_in,
                              void* d_out, int out_size, void* d_ws, size_t ws_size,
                              hipStream_t stream) {
  const int*   positions = (const int*)d_in[0];
  const float* hs    = (const float*)d_in[1];
  const float* resid = (const float*)d_in[2];
  const float* ln1w  = (const float*)d_in[3];
  const float* ln2w  = (const float*)d_in[4];
  const float* wq    = (const float*)d_in[5];
  const float* wk    = (const float*)d_in[6];
  const float* wv    = (const float*)d_in[7];
  const float* wo    = (const float*)d_in[8];
  const float* gatew = (const float*)d_in[9];
  const float* w1    = (const float*)d_in[10];
  const float* w3    = (const float*)d_in[11];
  const float* w2    = (const float*)d_in[12];
  float* dout = (float*)d_out;
  float* res2 = dout + (size_t)Tt * Hh;

  char* wp = (char*)d_ws;
  auto take = [&](size_t bytes) -> void* {
    void* p = (void*)wp;
    wp += (bytes + 255) & ~(size_t)255;
    return p;
  };
  u16*   qkvT  = (u16*)  take((size_t)3072 * 2048 * 2);
  u16*   qkvTl = (u16*)  take((size_t)3072 * 2048 * 2);
  u16*   woT   = (u16*)  take((size_t)2048 * 2048 * 2);
  u16*   w1T   = (u16*)  take((size_t)8 * 4096 * 2048 * 2);
  u16*   w3T   = (u16*)  take((size_t)8 * 4096 * 2048 * 2);
  u16*   w2T   = (u16*)  take((size_t)8 * 2048 * 4096 * 2);
  float* resf  = (float*)take((size_t)Tt * Hh * 4);            // 16 MB ┐
  u16*   hb    = (u16*)  take((size_t)Tt * Hh * 2);            //  8 MB │ dead after attn/wo-GEMM;
  u16*   hblo  = (u16*)  take((size_t)Tt * Hh * 2);            //  8 MB │ reused as x1 scratch
  float* qkvf  = (float*)take((size_t)Tt * 3072 * 4);          // 24 MB │ (4096*4096*4 = 64 MB,
  u16*   qhi   = (u16*)  take((size_t)Tt * 2048 * 2);          //  8 MB ┘  exactly this span)
  u16*   qlo   = (u16*)  take((size_t)Tt * 2048 * 2);
  u16*   khi   = (u16*)  take((size_t)Tt * 512 * 2);
  u16*   klo   = (u16*)  take((size_t)Tt * 512 * 2);
  u16*   vb2   = (u16*)  take((size_t)Tt * 512 * 2);
  u16*   attnb = (u16*)  take((size_t)Tt * 2048 * 2);
  u16*   h2b   = (u16*)  take((size_t)Tt * Hh * 2);
  u16*   gbuf  = (u16*)  take((size_t)(4096 + 128) * 4096 * 2);
  float* outk  = (float*)take((size_t)2 * Tt * Hh * 4);
  float* Gb    = (float*)take((size_t)2048 * 8 * 4);
  float* WGb   = (float*)take((size_t)2048 * 8 * 4);
  float* resGb = (float*)take((size_t)Tt * 8 * 4);
  float* VGb   = (float*)take((size_t)16 * Tt * 8 * 4);
  float* pvgp  = (float*)take((size_t)16 * Tt * 8 * 4);
  int*   tok   = (int*)  take((size_t)8 * 2048 * 4);
  float* wgt   = (float*)take((size_t)8 * 2048 * 4);
  int*   jid   = (int*)  take((size_t)8 * 2048 * 4);
  int*   cnt   = (int*)  take(64);
  if ((size_t)(wp - (char*)d_ws) > ws_size) return;
  // x1 scratch (4096 x 4096 f32 = 64 MB) aliases resf..qhi (16+8+8+24+8 = 64 MB),
  // all dead by the time the MoE GEMMs run.
  float* x1buf = resf;

  k_zero<<<1, 64, 0, stream>>>(cnt);
  k_addnorm<<<Tt, 256, 0, stream>>>(hs, resid, ln1w, resf, hb, hblo);
  k_transpose2_64<<<dim3(32, 32, 1), 256, 0, stream>>>(wq, qkvT, qkvTl, 2048, 2048);
  k_transpose2_64<<<dim3(32, 8, 1), 256, 0, stream>>>(wk, qkvT + (size_t)2048 * 2048,
                                                      qkvTl + (size_t)2048 * 2048, 2048, 512);
  k_transpose2_64<<<dim3(32, 8, 1), 256, 0, stream>>>(wv, qkvT + (size_t)2560 * 2048,
                                                      qkvTl + (size_t)2560 * 2048, 2048, 512);
  k_transpose64<<<dim3(32, 32, 1), 256, 0, stream>>>(wo, woT, 2048, 2048);
  k_transpose64<<<dim3(32, 64, 8), 256, 0, stream>>>(w1, w1T, 2048, 4096);
  k_transpose64<<<dim3(32, 64, 8), 256, 0, stream>>>(w3, w3T, 2048, 4096);
  k_transpose64<<<dim3(64, 32, 8), 256, 0, stream>>>(w2, w2T, 4096, 2048);
  k_G<<<64, 256, 0, stream>>>(ln2w, gatew, Gb);
  k_WG<<<64, 256, 0, stream>>>(wo, Gb, WGb);
  k_resG<<<64, 256, 0, stream>>>(resf, Gb, resGb);
  gemm_qkv<<<dim3(16, 24, 1), 256, 0, stream>>>(hb, hblo, qkvT, qkvTl, qkvf);
  k_rope<<<Tt, 256, 0, stream>>>(positions, qkvf, qhi, qlo, khi, klo, vb2);
  k_VG<<<1024, 256, 0, stream>>>(qkvf, WGb, VGb);
  k_attn2<<<dim3(32, 16, 1), 256, 0, stream>>>(qhi, qlo, khi, klo, vb2, VGb, attnb, pvgp);
  gemm_bt<1><<<dim3(16, 16, 1), 256, 0, stream>>>(attnb, woT, res2, resf, 2048, 2048);
  k_ln2gate<<<Tt, 256, 0, stream>>>(res2, ln2w, resGb, pvgp, h2b, cnt, tok, wgt, jid);
  gemm_m13<0><<<dim3(32, 16, 8), 256, 0, stream>>>(h2b, w1T, gbuf, x1buf, cnt, tok);
  gemm_m13<1><<<dim3(32, 16, 8), 256, 0, stream>>>(h2b, w3T, gbuf, x1buf, cnt, tok);
  gemm2k<<<dim3(16, 16, 8), 256, 0, stream>>>(gbuf, w2T, outk, cnt, tok, wgt, jid);
  k_combine<<<4096, 256, 0, stream>>>(outk, dout);
}

// Round 2
// 1238.977 us; speedup vs baseline: 1.1046x; 1.0591x over previous
//
#include <hip/hip_runtime.h>
#include <math.h>

typedef unsigned short u16;
typedef __attribute__((ext_vector_type(8))) short bf16x8;
typedef __attribute__((ext_vector_type(4))) float f32x4;

#define DI __device__ __forceinline__

constexpr int Tt  = 2048;   // tokens
constexpr int Hh  = 2048;   // hidden
constexpr int DFFd = 4096;  // expert ffn dim

DI u16 f2b(float f) {
  union { float f; unsigned u; } x; x.f = f;
  unsigned r = x.u + 0x7fffu + ((x.u >> 16) & 1u);
  return (u16)(r >> 16);
}
DI float b2f(u16 h) {
  union { unsigned u; float f; } x; x.u = ((unsigned)h) << 16; return x.f;
}
DI void gll16(const void* g, void* l) {
  __builtin_amdgcn_global_load_lds((const __attribute__((address_space(1))) unsigned int*)g,
                                   (__attribute__((address_space(3))) unsigned int*)l, 16, 0, 0);
}

// ---------------- fused add + RMSNorm (ln1), with hi/lo bf16 split ----------------
__global__ void k_addnorm(const float* __restrict__ hs, const float* __restrict__ resid,
                          const float* __restrict__ w, float* __restrict__ resf,
                          u16* __restrict__ hb, u16* __restrict__ hblo) {
  const int t = blockIdx.x, tid = threadIdx.x, lane = tid & 63, wid = tid >> 6;
  __shared__ float red[4];
  const size_t base = (size_t)t * Hh;
  float4 a = *(const float4*)(hs + base + tid * 4);
  float4 b = *(const float4*)(resid + base + tid * 4);
  float4 c = *(const float4*)(hs + base + 1024 + tid * 4);
  float4 d = *(const float4*)(resid + base + 1024 + tid * 4);
  float4 r1 = {a.x + b.x, a.y + b.y, a.z + b.z, a.w + b.w};
  float4 r2 = {c.x + d.x, c.y + d.y, c.z + d.z, c.w + d.w};
  *(float4*)(resf + base + tid * 4) = r1;
  *(float4*)(resf + base + 1024 + tid * 4) = r2;
  float ss = r1.x*r1.x + r1.y*r1.y + r1.z*r1.z + r1.w*r1.w
           + r2.x*r2.x + r2.y*r2.y + r2.z*r2.z + r2.w*r2.w;
#pragma unroll
  for (int m = 1; m < 64; m <<= 1) ss += __shfl_xor(ss, m);
  if (lane == 0) red[wid] = ss;
  __syncthreads();
  float tot = red[0] + red[1] + red[2] + red[3];
  float rstd = rsqrtf(tot * (1.f / Hh) + 1e-5f);
  float4 w1v = *(const float4*)(w + tid * 4);
  float4 w2v = *(const float4*)(w + 1024 + tid * 4);
  float hv[8];
  hv[0] = r1.x * rstd * w1v.x; hv[1] = r1.y * rstd * w1v.y;
  hv[2] = r1.z * rstd * w1v.z; hv[3] = r1.w * rstd * w1v.w;
  hv[4] = r2.x * rstd * w2v.x; hv[5] = r2.y * rstd * w2v.y;
  hv[6] = r2.z * rstd * w2v.z; hv[7] = r2.w * rstd * w2v.w;
  ushort4 o1, o2, l1, l2;
  u16 h;
  h = f2b(hv[0]); o1.x = h; l1.x = f2b(hv[0] - b2f(h));
  h = f2b(hv[1]); o1.y = h; l1.y = f2b(hv[1] - b2f(h));
  h = f2b(hv[2]); o1.z = h; l1.z = f2b(hv[2] - b2f(h));
  h = f2b(hv[3]); o1.w = h; l1.w = f2b(hv[3] - b2f(h));
  h = f2b(hv[4]); o2.x = h; l2.x = f2b(hv[4] - b2f(h));
  h = f2b(hv[5]); o2.y = h; l2.y = f2b(hv[5] - b2f(h));
  h = f2b(hv[6]); o2.z = h; l2.z = f2b(hv[6] - b2f(h));
  h = f2b(hv[7]); o2.w = h; l2.w = f2b(hv[7] - b2f(h));
  *(ushort4*)(hb + base + tid * 4) = o1;
  *(ushort4*)(hb + base + 1024 + tid * 4) = o2;
  *(ushort4*)(hblo + base + tid * 4) = l1;
  *(ushort4*)(hblo + base + 1024 + tid * 4) = l2;
}

// ---------------- transpose f32 [K][N] -> bf16 [N][K], 64x64 tiles ----------------
__global__ void k_transpose64(const float* __restrict__ src, u16* __restrict__ dst,
                              int K, int N) {
  size_t zo = (size_t)blockIdx.z * K * N;
  src += zo; dst += zo;
  __shared__ float tl[64][65];
  const int t = threadIdx.x;
  const int k0 = blockIdx.x * 64, n0 = blockIdx.y * 64;
  int r = t >> 4, c = (t & 15) * 4;
#pragma unroll
  for (int u = 0; u < 4; u++) {
    float4 v = *(const float4*)(src + (size_t)(k0 + r + u * 16) * N + n0 + c);
    tl[r + u * 16][c] = v.x; tl[r + u * 16][c + 1] = v.y;
    tl[r + u * 16][c + 2] = v.z; tl[r + u * 16][c + 3] = v.w;
  }
  __syncthreads();
  int n = t >> 2, kc = (t & 3) * 16;
  __align__(16) u16 tmp[16];
#pragma unroll
  for (int i = 0; i < 16; i++) tmp[i] = f2b(tl[kc + i][n]);
  uint4* dp = (uint4*)(dst + (size_t)(n0 + n) * K + k0 + kc);
  dp[0] = ((uint4*)tmp)[0];
  dp[1] = ((uint4*)tmp)[1];
}

// ---------------- transpose f32 [K][N] -> bf16 hi/lo [N][K], 64x64 tiles ----------------
__global__ void k_transpose2_64(const float* __restrict__ src, u16* __restrict__ dhi,
                                u16* __restrict__ dlo, int K, int N) {
  __shared__ float tl[64][65];
  const int t = threadIdx.x;
  const int k0 = blockIdx.x * 64, n0 = blockIdx.y * 64;
  int r = t >> 4, c = (t & 15) * 4;
#pragma unroll
  for (int u = 0; u < 4; u++) {
    float4 v = *(const float4*)(src + (size_t)(k0 + r + u * 16) * N + n0 + c);
    tl[r + u * 16][c] = v.x; tl[r + u * 16][c + 1] = v.y;
    tl[r + u * 16][c + 2] = v.z; tl[r + u * 16][c + 3] = v.w;
  }
  __syncthreads();
  int n = t >> 2, kc = (t & 3) * 16;
  __align__(16) u16 th[16], tlo[16];
#pragma unroll
  for (int i = 0; i < 16; i++) {
    float x = tl[kc + i][n];
    u16 hx = f2b(x);
    th[i] = hx; tlo[i] = f2b(x - b2f(hx));
  }
  uint4* dph = (uint4*)(dhi + (size_t)(n0 + n) * K + k0 + kc);
  dph[0] = ((uint4*)th)[0]; dph[1] = ((uint4*)th)[1];
  uint4* dpl = (uint4*)(dlo + (size_t)(n0 + n) * K + k0 + kc);
  dpl[0] = ((uint4*)tlo)[0]; dpl[1] = ((uint4*)tlo)[1];
}

// ---------------- split-bf16 GEMM: C[M,3072] = (Ahi+Alo)[M,2048] * (Bhi+Blo)^T ----------------
__launch_bounds__(256, 2)
__global__ void gemm_qkv(const u16* __restrict__ Ahi, const u16* __restrict__ Alo,
                         const u16* __restrict__ Bhi, const u16* __restrict__ Blo,
                         float* __restrict__ C) {
  __shared__ __align__(16) u16 Ah[2][128 * 32];
  __shared__ __align__(16) u16 Al[2][128 * 32];
  __shared__ __align__(16) u16 Bh[2][128 * 32];
  __shared__ __align__(16) u16 Bl[2][128 * 32];
  const int tid = threadIdx.x;
  const int wid = tid >> 6, lane = tid & 63, lr = lane & 15, lg = lane >> 4;
  const int m0 = blockIdx.x * 128, n0 = blockIdx.y * 128;
  const int wm = (wid >> 1) * 64, wn = (wid & 1) * 64;
  const int c0 = tid, c1 = tid + 256;
  const int ss0 = ((c0 & 3) ^ ((c0 >> 3) & 3)) * 8;
  const int ss1 = ((c1 & 3) ^ ((c1 >> 3) & 3)) * 8;
  const int fs = (lg ^ ((lr >> 1) & 3)) * 8;
  const size_t ao0 = (size_t)(m0 + (c0 >> 2)) * 2048 + ss0;
  const size_t ao1 = (size_t)(m0 + (c1 >> 2)) * 2048 + ss1;
  const size_t bo0 = (size_t)(n0 + (c0 >> 2)) * 2048 + ss0;
  const size_t bo1 = (size_t)(n0 + (c1 >> 2)) * 2048 + ss1;
  f32x4 zv = {0.f, 0.f, 0.f, 0.f};
  f32x4 acc[4][4];
#pragma unroll
  for (int i = 0; i < 4; i++)
#pragma unroll
    for (int j = 0; j < 4; j++) acc[i][j] = zv;
  const int NT = 2048 >> 5;
  gll16(Ahi + ao0, &Ah[0][c0 * 8]); gll16(Ahi + ao1, &Ah[0][c1 * 8]);
  gll16(Alo + ao0, &Al[0][c0 * 8]); gll16(Alo + ao1, &Al[0][c1 * 8]);
  gll16(Bhi + bo0, &Bh[0][c0 * 8]); gll16(Bhi + bo1, &Bh[0][c1 * 8]);
  gll16(Blo + bo0, &Bl[0][c0 * 8]); gll16(Blo + bo1, &Bl[0][c1 * 8]);
  int cur = 0;
  for (int t = 0; t < NT; ++t) {
    __syncthreads();
    if (t + 1 < NT) {
      int ko = (t + 1) << 5;
      gll16(Ahi + ao0 + ko, &Ah[cur ^ 1][c0 * 8]); gll16(Ahi + ao1 + ko, &Ah[cur ^ 1][c1 * 8]);
      gll16(Alo + ao0 + ko, &Al[cur ^ 1][c0 * 8]); gll16(Alo + ao1 + ko, &Al[cur ^ 1][c1 * 8]);
      gll16(Bhi + bo0 + ko, &Bh[cur ^ 1][c0 * 8]); gll16(Bhi + bo1 + ko, &Bh[cur ^ 1][c1 * 8]);
      gll16(Blo + bo0 + ko, &Bl[cur ^ 1][c0 * 8]); gll16(Blo + bo1 + ko, &Bl[cur ^ 1][c1 * 8]);
    }
    bf16x8 ah[4], al[4], bh[4], bl[4];
#pragma unroll
    for (int i = 0; i < 4; i++) {
      ah[i] = *(const bf16x8*)&Ah[cur][(wm + i * 16 + lr) * 32 + fs];
      al[i] = *(const bf16x8*)&Al[cur][(wm + i * 16 + lr) * 32 + fs];
    }
#pragma unroll
    for (int j = 0; j < 4; j++) {
      bh[j] = *(const bf16x8*)&Bh[cur][(wn + j * 16 + lr) * 32 + fs];
      bl[j] = *(const bf16x8*)&Bl[cur][(wn + j * 16 + lr) * 32 + fs];
    }
#pragma unroll
    for (int i = 0; i < 4; i++)
#pragma unroll
      for (int j = 0; j < 4; j++) {
        acc[i][j] = __builtin_amdgcn_mfma_f32_16x16x32_bf16(ah[i], bh[j], acc[i][j], 0, 0, 0);
        acc[i][j] = __builtin_amdgcn_mfma_f32_16x16x32_bf16(ah[i], bl[j], acc[i][j], 0, 0, 0);
        acc[i][j] = __builtin_amdgcn_mfma_f32_16x16x32_bf16(al[i], bh[j], acc[i][j], 0, 0, 0);
      }
    cur ^= 1;
  }
#pragma unroll
  for (int i = 0; i < 4; i++) {
    const int row = m0 + wm + i * 16 + lg * 4;
#pragma unroll
    for (int j = 0; j < 4; j++) {
      const int col = n0 + wn + j * 16 + lr;
#pragma unroll
      for (int r = 0; r < 4; r++)
        C[(size_t)(row + r) * 3072 + col] = acc[i][j][r];
    }
  }
}

// ---------------- GEMM C[M,N] = A[M,K]bf16 * BT[N,K]bf16 (+residual) ----------------
template <int MODE>
__launch_bounds__(256, 3)
__global__ void gemm_bt(const u16* __restrict__ A, const u16* __restrict__ BT,
                        float* __restrict__ C, const float* __restrict__ addf,
                        int N, int K) {
  __shared__ __align__(16) u16 Albuf[2][128 * 32];
  __shared__ __align__(16) u16 Blbuf[2][128 * 32];
  const int tid = threadIdx.x;
  const int wid = tid >> 6, lane = tid & 63, lr = lane & 15, lg = lane >> 4;
  const int m0 = blockIdx.x * 128, n0 = blockIdx.y * 128;
  const int wm = (wid >> 1) * 64, wn = (wid & 1) * 64;
  const int c0 = tid, c1 = tid + 256;
  const int ss0 = ((c0 & 3) ^ ((c0 >> 3) & 3)) * 8;
  const int ss1 = ((c1 & 3) ^ ((c1 >> 3) & 3)) * 8;
  const int fs = (lg ^ ((lr >> 1) & 3)) * 8;
  const u16* a0 = A + (size_t)(m0 + (c0 >> 2)) * K + ss0;
  const u16* a1 = A + (size_t)(m0 + (c1 >> 2)) * K + ss1;
  const u16* b0 = BT + (size_t)(n0 + (c0 >> 2)) * K + ss0;
  const u16* b1 = BT + (size_t)(n0 + (c1 >> 2)) * K + ss1;
  f32x4 zv = {0.f, 0.f, 0.f, 0.f};
  f32x4 acc[4][4];
#pragma unroll
  for (int i = 0; i < 4; i++)
#pragma unroll
    for (int j = 0; j < 4; j++) acc[i][j] = zv;
  const int NT = K >> 5;
  gll16(a0, &Albuf[0][c0 * 8]); gll16(a1, &Albuf[0][c1 * 8]);
  gll16(b0, &Blbuf[0][c0 * 8]); gll16(b1, &Blbuf[0][c1 * 8]);
  int cur = 0;
  for (int t = 0; t < NT; ++t) {
    __syncthreads();
    if (t + 1 < NT) {
      int ko = (t + 1) << 5;
      gll16(a0 + ko, &Albuf[cur ^ 1][c0 * 8]); gll16(a1 + ko, &Albuf[cur ^ 1][c1 * 8]);
      gll16(b0 + ko, &Blbuf[cur ^ 1][c0 * 8]); gll16(b1 + ko, &Blbuf[cur ^ 1][c1 * 8]);
    }
    bf16x8 af[4], bf[4];
#pragma unroll
    for (int i = 0; i < 4; i++) af[i] = *(const bf16x8*)&Albuf[cur][(wm + i * 16 + lr) * 32 + fs];
#pragma unroll
    for (int j = 0; j < 4; j++) bf[j] = *(const bf16x8*)&Blbuf[cur][(wn + j * 16 + lr) * 32 + fs];
#pragma unroll
    for (int i = 0; i < 4; i++)
#pragma unroll
      for (int j = 0; j < 4; j++)
        acc[i][j] = __builtin_amdgcn_mfma_f32_16x16x32_bf16(af[i], bf[j], acc[i][j], 0, 0, 0);
    cur ^= 1;
  }
#pragma unroll
  for (int i = 0; i < 4; i++) {
    const int row = m0 + wm + i * 16 + lg * 4;
#pragma unroll
    for (int j = 0; j < 4; j++) {
      const int col = n0 + wn + j * 16 + lr;
#pragma unroll
      for (int r = 0; r < 4; r++) {
        float v = acc[i][j][r];
        if (MODE == 1) v += addf[(size_t)(row + r) * N + col];
        C[(size_t)(row + r) * N + col] = v;
      }
    }
  }
}

// ---------------- RoPE + bf16 hi/lo pack of q/k, bf16 v ----------------
__global__ void k_rope(const int* __restrict__ pos, const float* __restrict__ qkvf,
                       u16* __restrict__ qhi, u16* __restrict__ qlo,
                       u16* __restrict__ khi, u16* __restrict__ klo,
                       u16* __restrict__ vb) {
  __shared__ float invtab[64];
  const int t = blockIdx.x, tid = threadIdx.x;
  if (tid < 64) invtab[tid] = 1.0f / (float)pow(1.0e6, (double)tid / 64.0);
  __syncthreads();
  const float p = (float)pos[t];
  const float* src = qkvf + (size_t)t * 3072;
#pragma unroll
  for (int it = 0; it < 4; ++it) {
    int idx = tid + it * 256;
    int head = idx >> 6, i = idx & 63;
    float ang = p * invtab[i];
    float cc, ssn;
    sincosf(ang, &ssn, &cc);
    float x1 = src[head * 128 + i], x2 = src[head * 128 + i + 64];
    float y1 = x1 * cc - x2 * ssn;
    float y2 = x2 * cc + x1 * ssn;
    u16 h1 = f2b(y1), h2 = f2b(y2);
    size_t o1 = (size_t)t * 2048 + head * 128 + i;
    qhi[o1] = h1;      qlo[o1] = f2b(y1 - b2f(h1));
    qhi[o1 + 64] = h2; qlo[o1 + 64] = f2b(y2 - b2f(h2));
  }
  {
    int head = tid >> 6, i = tid & 63;
    float ang = p * invtab[i];
    float cc, ssn;
    sincosf(ang, &ssn, &cc);
    float x1 = src[2048 + head * 128 + i], x2 = src[2048 + head * 128 + i + 64];
    float y1 = x1 * cc - x2 * ssn;
    float y2 = x2 * cc + x1 * ssn;
    u16 h1 = f2b(y1), h2 = f2b(y2);
    size_t o1 = (size_t)t * 512 + head * 128 + i;
    khi[o1] = h1;      klo[o1] = f2b(y1 - b2f(h1));
    khi[o1 + 64] = h2; klo[o1 + 64] = f2b(y2 - b2f(h2));
  }
#pragma unroll
  for (int u = 0; u < 2; ++u) {
    int ccol = tid + u * 256;
    vb[(size_t)t * 512 + ccol] = f2b(src[2560 + ccol]);
  }
}

// ---------------- tiny f32 helpers for the accurate gate path ----------------
__global__ void k_G(const float* __restrict__ ln2w, const float* __restrict__ gw,
                    float* __restrict__ G) {
  int i = blockIdx.x * 256 + threadIdx.x;   // 2048*8
  G[i] = ln2w[i >> 3] * gw[i];
}
__global__ void k_WG(const float* __restrict__ wo, const float* __restrict__ G,
                     float* __restrict__ WG) {
  int i = blockIdx.x * 256 + threadIdx.x;   // 2048*8
  int r = i >> 3, e = i & 7;
  const float* wr_ = wo + (size_t)r * 2048;
  float s0 = 0, s1 = 0, s2 = 0, s3 = 0;
  for (int c = 0; c < 2048; c += 4) {
    s0 += wr_[c] * G[c * 8 + e];
    s1 += wr_[c + 1] * G[(c + 1) * 8 + e];
    s2 += wr_[c + 2] * G[(c + 2) * 8 + e];
    s3 += wr_[c + 3] * G[(c + 3) * 8 + e];
  }
  WG[i] = (s0 + s1) + (s2 + s3);
}
__global__ void k_resG(const float* __restrict__ resf, const float* __restrict__ G,
                       float* __restrict__ resG) {
  int i = blockIdx.x * 256 + threadIdx.x;   // 2048*8
  int t = i >> 3, e = i & 7;
  const float* rr = resf + (size_t)t * 2048;
  float s0 = 0, s1 = 0, s2 = 0, s3 = 0;
  for (int c = 0; c < 2048; c += 4) {
    s0 += rr[c] * G[c * 8 + e];
    s1 += rr[c + 1] * G[(c + 1) * 8 + e];
    s2 += rr[c + 2] * G[(c + 2) * 8 + e];
    s3 += rr[c + 3] * G[(c + 3) * 8 + e];
  }
  resG[i] = (s0 + s1) + (s2 + s3);
}
__global__ void k_VG(const float* __restrict__ qkvf, const float* __restrict__ WG,
                     float* __restrict__ VG) {
  int i = blockIdx.x * 256 + threadIdx.x;   // 16*2048*8
  int e = i & 7, t = (i >> 3) & 2047, h = i >> 14;
  const float* vr = qkvf + (size_t)t * 3072 + 2560 + (h >> 2) * 128;
  const float* wgr = WG + (size_t)(h * 128) * 8 + e;
  float s = 0;
#pragma unroll 4
  for (int d = 0; d < 128; d++) s += vr[d] * wgr[d * 8];
  VG[i] = s;   // layout [h][t][e]
}

// ---------------- merged flash attention: accurate S (3-term) shared by
// PV (bf16 main path) and the p@VG gate path. Q direct to registers.
// Causal-balance: grid.x=16, each block does q-tile pair {31-x, x} ->
// exactly 33 K-tile iterations per block (was 1..32 imbalanced, worst CU 64).
// VG per-lane in registers (was ~128 ds_read_b32/lane/tile from LDS). ----------------
__launch_bounds__(256, 2)
__global__ void k_attn2(const u16* __restrict__ qh, const u16* __restrict__ qlo,
                        const u16* __restrict__ kh, const u16* __restrict__ klo,
                        const u16* __restrict__ vb, const float* __restrict__ vg,
                        u16* __restrict__ attnb, float* __restrict__ pvgp) {
  __shared__ __align__(16) u16 Kh[64 * 128];
  __shared__ __align__(16) u16 Kl[64 * 128];
  __shared__ __align__(16) u16 VTl[128 * 64];
  __shared__ __align__(16) u16 Pl[4][16 * 72];
  const int tid = threadIdx.x, wid = tid >> 6, lane = tid & 63, lr = lane & 15, lg = lane >> 4;
  const int h = blockIdx.y, hk = h >> 2, wr = wid * 16;
  f32x4 zv = {0.f, 0.f, 0.f, 0.f};

  for (int half = 0; half < 2; ++half) {
    const int qt = half ? blockIdx.x : 31 - blockIdx.x;   // pair {31-x, x}
    const int q0 = qt * 64;
    float m_[4], l_[4], avg[4][8];
    f32x4 accO[8];
#pragma unroll
    for (int r = 0; r < 4; r++) {
      m_[r] = -3e38f; l_[r] = 0.f;
#pragma unroll
      for (int e = 0; e < 8; e++) avg[r][e] = 0.f;
    }
#pragma unroll
    for (int d = 0; d < 8; d++) accO[d] = zv;
    // Q fragments straight from global (once per q-tile)
    bf16x8 aqh[4], aql[4];
    {
      const size_t qb = (size_t)(q0 + wr + lr) * 2048 + h * 128 + lg * 8;
#pragma unroll
      for (int kk = 0; kk < 4; kk++) {
        aqh[kk] = *(const bf16x8*)(qh + qb + kk * 32);
        aql[kk] = *(const bf16x8*)(qlo + qb + kk * 32);
      }
    }
    const int nk = qt + 1;
    for (int kt = 0; kt < nk; ++kt) {
      const int s0 = kt * 64;
      __syncthreads();
#pragma unroll
      for (int i = 0; i < 4; i++) {
        int c = tid + i * 256;
        int s = c >> 4, b = (c & 15) * 8;
        size_t go = (size_t)(s0 + s) * 512 + hk * 128 + (b ^ ((s & 7) << 3));
        gll16(kh + go, &Kh[c * 8]);
        gll16(klo + go, &Kl[c * 8]);
      }
      {
        int s = tid >> 2;
        const u16* vsrc = vb + (size_t)(s0 + s) * 512 + hk * 128 + (tid & 3) * 32;
#pragma unroll
        for (int u = 0; u < 4; u++) {
          uint4 wv = *(const uint4*)(vsrc + u * 8);
          const u16* tp = (const u16*)&wv;
          int d0b = (tid & 3) * 32 + u * 8;
          int scol = s ^ (((d0b >> 3) & 7) << 3);
#pragma unroll
          for (int ii = 0; ii < 8; ii++) VTl[(d0b + ii) * 64 + scol] = tp[ii];
        }
      }
      // per-lane VG rows (gate path) -> registers, coalesced float4 pairs
      float vgr[4][8];
#pragma unroll
      for (int ct = 0; ct < 4; ct++) {
        const float* vp = vg + ((size_t)h * 2048 + s0 + ct * 16 + lr) * 8;
        float4 u0 = *(const float4*)vp;
        float4 u1 = *(const float4*)(vp + 4);
        vgr[ct][0] = u0.x; vgr[ct][1] = u0.y; vgr[ct][2] = u0.z; vgr[ct][3] = u0.w;
        vgr[ct][4] = u1.x; vgr[ct][5] = u1.y; vgr[ct][6] = u1.z; vgr[ct][7] = u1.w;
      }
      __syncthreads();
      f32x4 accS[4];
#pragma unroll
      for (int ct = 0; ct < 4; ct++) accS[ct] = zv;
#pragma unroll
      for (int kk = 0; kk < 4; kk++) {
#pragma unroll
        for (int ct = 0; ct < 4; ct++) {
          int off = (ct * 16 + lr) * 128 + ((kk * 32 + lg * 8) ^ ((lr & 7) << 3));
          bf16x8 bh = *(const bf16x8*)&Kh[off];
          bf16x8 bl = *(const bf16x8*)&Kl[off];
          accS[ct] = __builtin_amdgcn_mfma_f32_16x16x32_bf16(aqh[kk], bh, accS[ct], 0, 0, 0);
          accS[ct] = __builtin_amdgcn_mfma_f32_16x16x32_bf16(aqh[kk], bl, accS[ct], 0, 0, 0);
          accS[ct] = __builtin_amdgcn_mfma_f32_16x16x32_bf16(aql[kk], bh, accS[ct], 0, 0, 0);
        }
      }
      const bool diag = (kt == qt);
      float alpha[4];
#pragma unroll
      for (int r = 0; r < 4; r++) {
        float sv[4];
        float mx = -3e38f;
#pragma unroll
        for (int ct = 0; ct < 4; ct++) {
          float sc = accS[ct][r] * 0.08838834764831845f;
          if (diag) {
            int col = ct * 16 + lr;
            int row = wr + lg * 4 + r;
            if (col > row) sc = -3e38f;
          }
          sv[ct] = sc; mx = fmaxf(mx, sc);
        }
#pragma unroll
        for (int m2 = 1; m2 < 16; m2 <<= 1) mx = fmaxf(mx, __shfl_xor(mx, m2));
        float mnew = fmaxf(m_[r], mx);
        float a = expf(m_[r] - mnew);
        float pv[4];
        float rs = 0.f;
#pragma unroll
        for (int ct = 0; ct < 4; ct++) { pv[ct] = expf(sv[ct] - mnew); rs += pv[ct]; }
#pragma unroll
        for (int m2 = 1; m2 < 16; m2 <<= 1) rs += __shfl_xor(rs, m2);
        l_[r] = l_[r] * a + rs;
        m_[r] = mnew;
        alpha[r] = a;
#pragma unroll
        for (int e = 0; e < 8; e++) avg[r][e] *= a;
#pragma unroll
        for (int ct = 0; ct < 4; ct++) {
          Pl[wid][(lg * 4 + r) * 72 + ct * 16 + lr] = f2b(pv[ct]);
#pragma unroll
          for (int e = 0; e < 8; e++) avg[r][e] += pv[ct] * vgr[ct][e];
        }
      }
#pragma unroll
      for (int d = 0; d < 8; d++)
#pragma unroll
        for (int r = 0; r < 4; r++) accO[d][r] *= alpha[r];
      // NOTE: no barrier here -- Pl[wid] is same-wave (in-order DS), VTl was
      // covered by the post-staging barrier; loop-top barrier guards re-staging.
#pragma unroll
      for (int ks = 0; ks < 2; ks++) {
        bf16x8 ap = *(const bf16x8*)&Pl[wid][lr * 72 + ks * 32 + lg * 8];
#pragma unroll
        for (int d0 = 0; d0 < 8; d0++) {
          int d = d0 * 16 + lr;
          int scol = (ks * 32 + lg * 8) ^ (((d >> 3) & 7) << 3);
          bf16x8 bv = *(const bf16x8*)&VTl[d * 64 + scol];
          accO[d0] = __builtin_amdgcn_mfma_f32_16x16x32_bf16(ap, bv, accO[d0], 0, 0, 0);
        }
      }
    }
#pragma unroll
    for (int d0 = 0; d0 < 8; d0++)
#pragma unroll
      for (int r = 0; r < 4; r++) {
        float v = accO[d0][r] / l_[r];
        attnb[(size_t)(q0 + wr + lg * 4 + r) * 2048 + h * 128 + d0 * 16 + lr] = f2b(v);
      }
#pragma unroll
    for (int m2 = 1; m2 < 16; m2 <<= 1)
#pragma unroll
      for (int r = 0; r < 4; r++)
#pragma unroll
        for (int e = 0; e < 8; e++) avg[r][e] += __shfl_xor(avg[r][e], m2);
#pragma unroll
    for (int r = 0; r < 4; r++) {
      int t = q0 + wr + lg * 4 + r;
      float inv = 1.f / l_[r];
#pragma unroll
      for (int e = 0; e < 8; e++)
        if (lr == e) pvgp[((size_t)h * 2048 + t) * 8 + e] = avg[r][e] * inv;
    }
  }
}

// ---------------- RMSNorm(ln2) + accurate-logit gate + top2 routing ----------------
__global__ void k_ln2gate(const float* __restrict__ res2, const float* __restrict__ w,
                          const float* __restrict__ resG, const float* __restrict__ pvgp,
                          u16* __restrict__ h2b,
                          int* __restrict__ cnt, int* __restrict__ tok,
                          float* __restrict__ wgt, int* __restrict__ jid) {
  const int t = blockIdx.x, tid = threadIdx.x, lane = tid & 63, wid = tid >> 6;
  __shared__ float red[4];
  const size_t base = (size_t)t * Hh;
  float4 r1 = *(const float4*)(res2 + base + tid * 4);
  float4 r2 = *(const float4*)(res2 + base + 1024 + tid * 4);
  float ss = r1.x*r1.x + r1.y*r1.y + r1.z*r1.z + r1.w*r1.w
           + r2.x*r2.x + r2.y*r2.y + r2.z*r2.z + r2.w*r2.w;
#pragma unroll
  for (int m = 1; m < 64; m <<= 1) ss += __shfl_xor(ss, m);
  if (lane == 0) red[wid] = ss;
  __syncthreads();
  float tot = red[0] + red[1] + red[2] + red[3];
  float rstd = rsqrtf(tot * (1.f / Hh) + 1e-5f);
  float4 w1v = *(const float4*)(w + tid * 4);
  float4 w2v = *(const float4*)(w + 1024 + tid * 4);
  ushort4 o1, o2;
  o1.x = f2b(r1.x * rstd * w1v.x); o1.y = f2b(r1.y * rstd * w1v.y);
  o1.z = f2b(r1.z * rstd * w1v.z); o1.w = f2b(r1.w * rstd * w1v.w);
  o2.x = f2b(r2.x * rstd * w2v.x); o2.y = f2b(r2.y * rstd * w2v.y);
  o2.z = f2b(r2.z * rstd * w2v.z); o2.w = f2b(r2.w * rstd * w2v.w);
  *(ushort4*)(h2b + base + tid * 4) = o1;
  *(ushort4*)(h2b + base + 1024 + tid * 4) = o2;
  if (tid == 0) {
    float lg8[8];
#pragma unroll
    for (int e = 0; e < 8; e++) {
      float s = resG[t * 8 + e];
      for (int hh = 0; hh < 16; hh++) s += pvgp[((size_t)hh * 2048 + t) * 8 + e];
      lg8[e] = s * rstd;
    }
    float mx = lg8[0];
#pragma unroll
    for (int e = 1; e < 8; e++) mx = fmaxf(mx, lg8[e]);
    float ex[8];
#pragma unroll
    for (int e = 0; e < 8; e++) ex[e] = expf(lg8[e] - mx);
    int i1 = 0; float v1 = ex[0];
#pragma unroll
    for (int e = 1; e < 8; e++) if (ex[e] > v1) { v1 = ex[e]; i1 = e; }
    int i2 = -1; float v2 = -1.f;
#pragma unroll
    for (int e = 0; e < 8; e++) if (e != i1 && ex[e] > v2) { v2 = ex[e]; i2 = e; }
    float inv = 1.f / (v1 + v2);
    int s1 = atomicAdd(&cnt[i1], 1);
    tok[i1 * 2048 + s1] = t; wgt[i1 * 2048 + s1] = v1 * inv; jid[i1 * 2048 + s1] = 0;
    int s2 = atomicAdd(&cnt[i2], 1);
    tok[i2 * 2048 + s2] = t; wgt[i2 * 2048 + s2] = v2 * inv; jid[i2 * 2048 + s2] = 1;
  }
}

// ---------------- MoE GEMM1, split into two single-B passes ----------------
template <int PHASE>
__launch_bounds__(256, 3)
__global__ void gemm_m13(const u16* __restrict__ h2b, const u16* __restrict__ wT,
                         u16* __restrict__ gbuf, float* __restrict__ x1,
                         const int* __restrict__ cnt, const int* __restrict__ tok) {
  const int e = blockIdx.z;
  const int cnt_e = cnt[e];
  const int m0 = blockIdx.y * 128;
  if (m0 >= cnt_e) return;
  int gb = 0;
#pragma unroll
  for (int i = 0; i < 8; i++) if (i < e) gb += cnt[i];
  __shared__ __align__(16) u16 Al[2][128 * 32];
  __shared__ __align__(16) u16 Bl[2][128 * 32];
  const int tid = threadIdx.x;
  const int wid = tid >> 6, lane = tid & 63, lr = lane & 15, lg = lane >> 4;
  const int n0 = blockIdx.x * 128;
  const int wm = (wid >> 1) * 64, wn = (wid & 1) * 64;
  const int c0 = tid, c1 = tid + 256;
  const int ss0 = ((c0 & 3) ^ ((c0 >> 3) & 3)) * 8;
  const int ss1 = ((c1 & 3) ^ ((c1 >> 3) & 3)) * 8;
  const int fs = (lg ^ ((lr >> 1) & 3)) * 8;
  int r0 = m0 + (c0 >> 2); if (r0 > cnt_e - 1) r0 = cnt_e - 1;
  int r1 = m0 + (c1 >> 2); if (r1 > cnt_e - 1) r1 = cnt_e - 1;
  const int tk0 = tok[e * 2048 + r0], tk1 = tok[e * 2048 + r1];
  const u16* a0 = h2b + (size_t)tk0 * 2048 + ss0;
  const u16* a1 = h2b + (size_t)tk1 * 2048 + ss1;
  const u16* b0 = wT + (size_t)e * DFFd * 2048 + (size_t)(n0 + (c0 >> 2)) * 2048 + ss0;
  const u16* b1 = wT + (size_t)e * DFFd * 2048 + (size_t)(n0 + (c1 >> 2)) * 2048 + ss1;
  f32x4 zv = {0.f, 0.f, 0.f, 0.f};
  f32x4 acc[4][4];
#pragma unroll
  for (int i = 0; i < 4; i++)
#pragma unroll
    for (int j = 0; j < 4; j++) acc[i][j] = zv;
  const int NT = 2048 >> 5;
  gll16(a0, &Al[0][c0 * 8]); gll16(a1, &Al[0][c1 * 8]);
  gll16(b0, &Bl[0][c0 * 8]); gll16(b1, &Bl[0][c1 * 8]);
  int cur = 0;
  for (int t = 0; t < NT; ++t) {
    __syncthreads();
    if (t + 1 < NT) {
      int ko = (t + 1) << 5;
      gll16(a0 + ko, &Al[cur ^ 1][c0 * 8]); gll16(a1 + ko, &Al[cur ^ 1][c1 * 8]);
      gll16(b0 + ko, &Bl[cur ^ 1][c0 * 8]); gll16(b1 + ko, &Bl[cur ^ 1][c1 * 8]);
    }
    bf16x8 af[4], bf[4];
#pragma unroll
    for (int i = 0; i < 4; i++) af[i] = *(const bf16x8*)&Al[cur][(wm + i * 16 + lr) * 32 + fs];
#pragma unroll
    for (int j = 0; j < 4; j++) bf[j] = *(const bf16x8*)&Bl[cur][(wn + j * 16 + lr) * 32 + fs];
#pragma unroll
    for (int i = 0; i < 4; i++)
#pragma unroll
      for (int j = 0; j < 4; j++)
        acc[i][j] = __builtin_amdgcn_mfma_f32_16x16x32_bf16(af[i], bf[j], acc[i][j], 0, 0, 0);
    cur ^= 1;
  }
#pragma unroll
  for (int i = 0; i < 4; i++) {
    const int slotb = m0 + wm + i * 16 + lg * 4;
#pragma unroll
    for (int j = 0; j < 4; j++) {
      const int col = n0 + wn + j * 16 + lr;
#pragma unroll
      for (int r = 0; r < 4; r++) {
        int slot = slotb + r;
        if (slot < cnt_e) {
          size_t o = (size_t)(gb + slot) * DFFd + col;
          if (PHASE == 0) {
            x1[o] = acc[i][j][r];
          } else {
            float xv = x1[o];
            float g = xv / (1.f + __expf(-xv)) * acc[i][j][r];
            gbuf[o] = f2b(g);
          }
        }
      }
    }
  }
}

// ---------------- MoE GEMM2: out_j[token] = w * (g @ w2) ----------------
__launch_bounds__(256, 3)
__global__ void gemm2k(const u16* __restrict__ gbuf, const u16* __restrict__ w2T,
                       float* __restrict__ outk, const int* __restrict__ cnt,
                       const int* __restrict__ tok, const float* __restrict__ wgt,
                       const int* __restrict__ jid) {
  const int e = blockIdx.z;
  const int cnt_e = cnt[e];
  const int m0 = blockIdx.y * 128;
  if (m0 >= cnt_e) return;
  int gb = 0;
#pragma unroll
  for (int i = 0; i < 8; i++) if (i < e) gb += cnt[i];
  __shared__ __align__(16) u16 Al[2][128 * 32];
  __shared__ __align__(16) u16 Bl[2][128 * 32];
  const int tid = threadIdx.x;
  const int wid = tid >> 6, lane = tid & 63, lr = lane & 15, lg = lane >> 4;
  const int n0 = blockIdx.x * 128;
  const int wm = (wid >> 1) * 64, wn = (wid & 1) * 64;
  const int c0 = tid, c1 = tid + 256;
  const int ss0 = ((c0 & 3) ^ ((c0 >> 3) & 3)) * 8;
  const int ss1 = ((c1 & 3) ^ ((c1 >> 3) & 3)) * 8;
  const int fs = (lg ^ ((lr >> 1) & 3)) * 8;
  const u16* A = gbuf + (size_t)gb * DFFd;
  const u16* a0 = A + (size_t)(m0 + (c0 >> 2)) * DFFd + ss0;
  const u16* a1 = A + (size_t)(m0 + (c1 >> 2)) * DFFd + ss1;
  const u16* b0 = w2T + (size_t)e * 2048 * DFFd + (size_t)(n0 + (c0 >> 2)) * DFFd + ss0;
  const u16* b1 = w2T + (size_t)e * 2048 * DFFd + (size_t)(n0 + (c1 >> 2)) * DFFd + ss1;
  f32x4 zv = {0.f, 0.f, 0.f, 0.f};
  f32x4 acc[4][4];
#pragma unroll
  for (int i = 0; i < 4; i++)
#pragma unroll
    for (int j = 0; j < 4; j++) acc[i][j] = zv;
  const int NT = DFFd >> 5;
  gll16(a0, &Al[0][c0 * 8]); gll16(a1, &Al[0][c1 * 8]);
  gll16(b0, &Bl[0][c0 * 8]); gll16(b1, &Bl[0][c1 * 8]);
  int cur = 0;
  for (int t = 0; t < NT; ++t) {
    __syncthreads();
    if (t + 1 < NT) {
      int ko = (t + 1) << 5;
      gll16(a0 + ko, &Al[cur ^ 1][c0 * 8]); gll16(a1 + ko, &Al[cur ^ 1][c1 * 8]);
      gll16(b0 + ko, &Bl[cur ^ 1][c0 * 8]); gll16(b1 + ko, &Bl[cur ^ 1][c1 * 8]);
    }
    bf16x8 af[4], bf[4];
#pragma unroll
    for (int i = 0; i < 4; i++) af[i] = *(const bf16x8*)&Al[cur][(wm + i * 16 + lr) * 32 + fs];
#pragma unroll
    for (int j = 0; j < 4; j++) bf[j] = *(const bf16x8*)&Bl[cur][(wn + j * 16 + lr) * 32 + fs];
#pragma unroll
    for (int i = 0; i < 4; i++)
#pragma unroll
      for (int j = 0; j < 4; j++)
        acc[i][j] = __builtin_amdgcn_mfma_f32_16x16x32_bf16(af[i], bf[j], acc[i][j], 0, 0, 0);
    cur ^= 1;
  }
#pragma unroll
  for (int i = 0; i < 4; i++) {
    const int slotb = m0 + wm + i * 16 + lg * 4;
#pragma unroll
    for (int r = 0; r < 4; r++) {
      int slot = slotb + r;
      if (slot < cnt_e) {
        int tkn = tok[e * 2048 + slot];
        float wv = wgt[e * 2048 + slot];
        int jj = jid[e * 2048 + slot];
        float* orow = outk + (size_t)jj * ((size_t)Tt * Hh) + (size_t)tkn * Hh;
#pragma unroll
        for (int j = 0; j < 4; j++) {
          const int col = n0 + wn + j * 16 + lr;
          orow[col] = wv * acc[i][j][r];
        }
      }
    }
  }
}

__global__ void k_zero(int* cnt) { if (threadIdx.x < 8) cnt[threadIdx.x] = 0; }

__global__ void k_combine(const float* __restrict__ outk, float* __restrict__ dout) {
  size_t i = ((size_t)blockIdx.x * 256 + threadIdx.x) * 4;
  float4 a = *(const float4*)(outk + i);
  float4 b = *(const float4*)(outk + (size_t)Tt * Hh + i);
  float4 o = {a.x + b.x, a.y + b.y, a.z + b.z, a.w + b.w};
  *(float4*)(dout + i) = o;
}

extern "C" void kernel_launch(void* const* d_in, const int* in_sizes, int n_in,
                              void* d_out, int out_size, void* d_ws, size_t ws_size,
                              hipStream_t stream) {
  const int*   positions = (const int*)d_in[0];
  const float* hs    = (const float*)d_in[1];
  const float* resid = (const float*)d_in[2];
  const float* ln1w  = (const float*)d_in[3];
  const float* ln2w  = (const float*)d_in[4];
  const float* wq    = (const float*)d_in[5];
  const float* wk    = (const float*)d_in[6];
  const float* wv    = (const float*)d_in[7];
  const float* wo    = (const float*)d_in[8];
  const float* gatew = (const float*)d_in[9];
  const float* w1    = (const float*)d_in[10];
  const float* w3    = (const float*)d_in[11];
  const float* w2    = (const float*)d_in[12];
  float* dout = (float*)d_out;
  float* res2 = dout + (size_t)Tt * Hh;

  char* wp = (char*)d_ws;
  auto take = [&](size_t bytes) -> void* {
    void* p = (void*)wp;
    wp += (bytes + 255) & ~(size_t)255;
    return p;
  };
  u16*   qkvT  = (u16*)  take((size_t)3072 * 2048 * 2);
  u16*   qkvTl = (u16*)  take((size_t)3072 * 2048 * 2);
  u16*   woT   = (u16*)  take((size_t)2048 * 2048 * 2);
  u16*   w1T   = (u16*)  take((size_t)8 * 4096 * 2048 * 2);
  u16*   w3T   = (u16*)  take((size_t)8 * 4096 * 2048 * 2);
  u16*   w2T   = (u16*)  take((size_t)8 * 2048 * 4096 * 2);
  float* resf  = (float*)take((size_t)Tt * Hh * 4);            // 16 MB ┐
  u16*   hb    = (u16*)  take((size_t)Tt * Hh * 2);            //  8 MB │ dead after attn/wo-GEMM;
  u16*   hblo  = (u16*)  take((size_t)Tt * Hh * 2);            //  8 MB │ reused as x1 scratch
  float* qkvf  = (float*)take((size_t)Tt * 3072 * 4);          // 24 MB │ (4096*4096*4 = 64 MB,
  u16*   qhi   = (u16*)  take((size_t)Tt * 2048 * 2);          //  8 MB ┘  exactly this span)
  u16*   qlo   = (u16*)  take((size_t)Tt * 2048 * 2);
  u16*   khi   = (u16*)  take((size_t)Tt * 512 * 2);
  u16*   klo   = (u16*)  take((size_t)Tt * 512 * 2);
  u16*   vb2   = (u16*)  take((size_t)Tt * 512 * 2);
  u16*   attnb = (u16*)  take((size_t)Tt * 2048 * 2);
  u16*   h2b   = (u16*)  take((size_t)Tt * Hh * 2);
  u16*   gbuf  = (u16*)  take((size_t)(4096 + 128) * 4096 * 2);
  float* outk  = (float*)take((size_t)2 * Tt * Hh * 4);
  float* Gb    = (float*)take((size_t)2048 * 8 * 4);
  float* WGb   = (float*)take((size_t)2048 * 8 * 4);
  float* resGb = (float*)take((size_t)Tt * 8 * 4);
  float* VGb   = (float*)take((size_t)16 * Tt * 8 * 4);
  float* pvgp  = (float*)take((size_t)16 * Tt * 8 * 4);
  int*   tok   = (int*)  take((size_t)8 * 2048 * 4);
  float* wgt   = (float*)take((size_t)8 * 2048 * 4);
  int*   jid   = (int*)  take((size_t)8 * 2048 * 4);
  int*   cnt   = (int*)  take(64);
  if ((size_t)(wp - (char*)d_ws) > ws_size) return;
  // x1 scratch (4096 x 4096 f32 = 64 MB) aliases resf..qhi (16+8+8+24+8 = 64 MB),
  // all dead by the time the MoE GEMMs run.
  float* x1buf = resf;

  k_zero<<<1, 64, 0, stream>>>(cnt);
  k_addnorm<<<Tt, 256, 0, stream>>>(hs, resid, ln1w, resf, hb, hblo);
  k_transpose2_64<<<dim3(32, 32, 1), 256, 0, stream>>>(wq, qkvT, qkvTl, 2048, 2048);
  k_transpose2_64<<<dim3(32, 8, 1), 256, 0, stream>>>(wk, qkvT + (size_t)2048 * 2048,
                                                      qkvTl + (size_t)2048 * 2048, 2048, 512);
  k_transpose2_64<<<dim3(32, 8, 1), 256, 0, stream>>>(wv, qkvT + (size_t)2560 * 2048,
                                                      qkvTl + (size_t)2560 * 2048, 2048, 512);
  k_transpose64<<<dim3(32, 32, 1), 256, 0, stream>>>(wo, woT, 2048, 2048);
  k_transpose64<<<dim3(32, 64, 8), 256, 0, stream>>>(w1, w1T, 2048, 4096);
  k_transpose64<<<dim3(32, 64, 8), 256, 0, stream>>>(w3, w3T, 2048, 4096);
  k_transpose64<<<dim3(64, 32, 8), 256, 0, stream>>>(w2, w2T, 4096, 2048);
  k_G<<<64, 256, 0, stream>>>(ln2w, gatew, Gb);
  k_WG<<<64, 256, 0, stream>>>(wo, Gb, WGb);
  k_resG<<<64, 256, 0, stream>>>(resf, Gb, resGb);
  gemm_qkv<<<dim3(16, 24, 1), 256, 0, stream>>>(hb, hblo, qkvT, qkvTl, qkvf);
  k_rope<<<Tt, 256, 0, stream>>>(positions, qkvf, qhi, qlo, khi, klo, vb2);
  k_VG<<<1024, 256, 0, stream>>>(qkvf, WGb, VGb);
  k_attn2<<<dim3(16, 16, 1), 256, 0, stream>>>(qhi, qlo, khi, klo, vb2, VGb, attnb, pvgp);
  gemm_bt<1><<<dim3(16, 16, 1), 256, 0, stream>>>(attnb, woT, res2, resf, 2048, 2048);
  k_ln2gate<<<Tt, 256, 0, stream>>>(res2, ln2w, resGb, pvgp, h2b, cnt, tok, wgt, jid);
  gemm_m13<0><<<dim3(32, 16, 8), 256, 0, stream>>>(h2b, w1T, gbuf, x1buf, cnt, tok);
  gemm_m13<1><<<dim3(32, 16, 8), 256, 0, stream>>>(h2b, w3T, gbuf, x1buf, cnt, tok);
  gemm2k<<<dim3(16, 16, 8), 256, 0, stream>>>(gbuf, w2T, outk, cnt, tok, wgt, jid);
  k_combine<<<4096, 256, 0, stream>>>(outk, dout);
}

// Round 3
// 1235.374 us; speedup vs baseline: 1.1078x; 1.0029x over previous
//
#include <hip/hip_runtime.h>
#include <math.h>

typedef unsigned short u16;
typedef __attribute__((ext_vector_type(8))) short bf16x8;
typedef __attribute__((ext_vector_type(4))) float f32x4;

#define DI __device__ __forceinline__

constexpr int Tt  = 2048;   // tokens
constexpr int Hh  = 2048;   // hidden
constexpr int DFFd = 4096;  // expert ffn dim

DI u16 f2b(float f) {
  union { float f; unsigned u; } x; x.f = f;
  unsigned r = x.u + 0x7fffu + ((x.u >> 16) & 1u);
  return (u16)(r >> 16);
}
DI float b2f(u16 h) {
  union { unsigned u; float f; } x; x.u = ((unsigned)h) << 16; return x.f;
}
DI void gll16(const void* g, void* l) {
  __builtin_amdgcn_global_load_lds((const __attribute__((address_space(1))) unsigned int*)g,
                                   (__attribute__((address_space(3))) unsigned int*)l, 16, 0, 0);
}

// ---------------- fused add + RMSNorm (ln1), with hi/lo bf16 split ----------------
__global__ void k_addnorm(const float* __restrict__ hs, const float* __restrict__ resid,
                          const float* __restrict__ w, float* __restrict__ resf,
                          u16* __restrict__ hb, u16* __restrict__ hblo) {
  const int t = blockIdx.x, tid = threadIdx.x, lane = tid & 63, wid = tid >> 6;
  __shared__ float red[4];
  const size_t base = (size_t)t * Hh;
  float4 a = *(const float4*)(hs + base + tid * 4);
  float4 b = *(const float4*)(resid + base + tid * 4);
  float4 c = *(const float4*)(hs + base + 1024 + tid * 4);
  float4 d = *(const float4*)(resid + base + 1024 + tid * 4);
  float4 r1 = {a.x + b.x, a.y + b.y, a.z + b.z, a.w + b.w};
  float4 r2 = {c.x + d.x, c.y + d.y, c.z + d.z, c.w + d.w};
  *(float4*)(resf + base + tid * 4) = r1;
  *(float4*)(resf + base + 1024 + tid * 4) = r2;
  float ss = r1.x*r1.x + r1.y*r1.y + r1.z*r1.z + r1.w*r1.w
           + r2.x*r2.x + r2.y*r2.y + r2.z*r2.z + r2.w*r2.w;
#pragma unroll
  for (int m = 1; m < 64; m <<= 1) ss += __shfl_xor(ss, m);
  if (lane == 0) red[wid] = ss;
  __syncthreads();
  float tot = red[0] + red[1] + red[2] + red[3];
  float rstd = rsqrtf(tot * (1.f / Hh) + 1e-5f);
  float4 w1v = *(const float4*)(w + tid * 4);
  float4 w2v = *(const float4*)(w + 1024 + tid * 4);
  float hv[8];
  hv[0] = r1.x * rstd * w1v.x; hv[1] = r1.y * rstd * w1v.y;
  hv[2] = r1.z * rstd * w1v.z; hv[3] = r1.w * rstd * w1v.w;
  hv[4] = r2.x * rstd * w2v.x; hv[5] = r2.y * rstd * w2v.y;
  hv[6] = r2.z * rstd * w2v.z; hv[7] = r2.w * rstd * w2v.w;
  ushort4 o1, o2, l1, l2;
  u16 h;
  h = f2b(hv[0]); o1.x = h; l1.x = f2b(hv[0] - b2f(h));
  h = f2b(hv[1]); o1.y = h; l1.y = f2b(hv[1] - b2f(h));
  h = f2b(hv[2]); o1.z = h; l1.z = f2b(hv[2] - b2f(h));
  h = f2b(hv[3]); o1.w = h; l1.w = f2b(hv[3] - b2f(h));
  h = f2b(hv[4]); o2.x = h; l2.x = f2b(hv[4] - b2f(h));
  h = f2b(hv[5]); o2.y = h; l2.y = f2b(hv[5] - b2f(h));
  h = f2b(hv[6]); o2.z = h; l2.z = f2b(hv[6] - b2f(h));
  h = f2b(hv[7]); o2.w = h; l2.w = f2b(hv[7] - b2f(h));
  *(ushort4*)(hb + base + tid * 4) = o1;
  *(ushort4*)(hb + base + 1024 + tid * 4) = o2;
  *(ushort4*)(hblo + base + tid * 4) = l1;
  *(ushort4*)(hblo + base + 1024 + tid * 4) = l2;
}

// ---------------- transpose f32 [K][N] -> bf16 [N][K], 64x64 tiles ----------------
__global__ void k_transpose64(const float* __restrict__ src, u16* __restrict__ dst,
                              int K, int N) {
  size_t zo = (size_t)blockIdx.z * K * N;
  src += zo; dst += zo;
  __shared__ float tl[64][65];
  const int t = threadIdx.x;
  const int k0 = blockIdx.x * 64, n0 = blockIdx.y * 64;
  int r = t >> 4, c = (t & 15) * 4;
#pragma unroll
  for (int u = 0; u < 4; u++) {
    float4 v = *(const float4*)(src + (size_t)(k0 + r + u * 16) * N + n0 + c);
    tl[r + u * 16][c] = v.x; tl[r + u * 16][c + 1] = v.y;
    tl[r + u * 16][c + 2] = v.z; tl[r + u * 16][c + 3] = v.w;
  }
  __syncthreads();
  int n = t >> 2, kc = (t & 3) * 16;
  __align__(16) u16 tmp[16];
#pragma unroll
  for (int i = 0; i < 16; i++) tmp[i] = f2b(tl[kc + i][n]);
  uint4* dp = (uint4*)(dst + (size_t)(n0 + n) * K + k0 + kc);
  dp[0] = ((uint4*)tmp)[0];
  dp[1] = ((uint4*)tmp)[1];
}

// ---------------- transpose f32 [K][N] -> bf16 hi/lo [N][K], 64x64 tiles ----------------
__global__ void k_transpose2_64(const float* __restrict__ src, u16* __restrict__ dhi,
                                u16* __restrict__ dlo, int K, int N) {
  __shared__ float tl[64][65];
  const int t = threadIdx.x;
  const int k0 = blockIdx.x * 64, n0 = blockIdx.y * 64;
  int r = t >> 4, c = (t & 15) * 4;
#pragma unroll
  for (int u = 0; u < 4; u++) {
    float4 v = *(const float4*)(src + (size_t)(k0 + r + u * 16) * N + n0 + c);
    tl[r + u * 16][c] = v.x; tl[r + u * 16][c + 1] = v.y;
    tl[r + u * 16][c + 2] = v.z; tl[r + u * 16][c + 3] = v.w;
  }
  __syncthreads();
  int n = t >> 2, kc = (t & 3) * 16;
  __align__(16) u16 th[16], tlo[16];
#pragma unroll
  for (int i = 0; i < 16; i++) {
    float x = tl[kc + i][n];
    u16 hx = f2b(x);
    th[i] = hx; tlo[i] = f2b(x - b2f(hx));
  }
  uint4* dph = (uint4*)(dhi + (size_t)(n0 + n) * K + k0 + kc);
  dph[0] = ((uint4*)th)[0]; dph[1] = ((uint4*)th)[1];
  uint4* dpl = (uint4*)(dlo + (size_t)(n0 + n) * K + k0 + kc);
  dpl[0] = ((uint4*)tlo)[0]; dpl[1] = ((uint4*)tlo)[1];
}

// ---------------- split-bf16 GEMM: C[M,3072] = (Ahi+Alo)[M,2048] * (Bhi+Blo)^T ----------------
__launch_bounds__(256, 2)
__global__ void gemm_qkv(const u16* __restrict__ Ahi, const u16* __restrict__ Alo,
                         const u16* __restrict__ Bhi, const u16* __restrict__ Blo,
                         float* __restrict__ C) {
  __shared__ __align__(16) u16 Ah[2][128 * 32];
  __shared__ __align__(16) u16 Al[2][128 * 32];
  __shared__ __align__(16) u16 Bh[2][128 * 32];
  __shared__ __align__(16) u16 Bl[2][128 * 32];
  const int tid = threadIdx.x;
  const int wid = tid >> 6, lane = tid & 63, lr = lane & 15, lg = lane >> 4;
  const int m0 = blockIdx.x * 128, n0 = blockIdx.y * 128;
  const int wm = (wid >> 1) * 64, wn = (wid & 1) * 64;
  const int c0 = tid, c1 = tid + 256;
  const int ss0 = ((c0 & 3) ^ ((c0 >> 3) & 3)) * 8;
  const int ss1 = ((c1 & 3) ^ ((c1 >> 3) & 3)) * 8;
  const int fs = (lg ^ ((lr >> 1) & 3)) * 8;
  const size_t ao0 = (size_t)(m0 + (c0 >> 2)) * 2048 + ss0;
  const size_t ao1 = (size_t)(m0 + (c1 >> 2)) * 2048 + ss1;
  const size_t bo0 = (size_t)(n0 + (c0 >> 2)) * 2048 + ss0;
  const size_t bo1 = (size_t)(n0 + (c1 >> 2)) * 2048 + ss1;
  f32x4 zv = {0.f, 0.f, 0.f, 0.f};
  f32x4 acc[4][4];
#pragma unroll
  for (int i = 0; i < 4; i++)
#pragma unroll
    for (int j = 0; j < 4; j++) acc[i][j] = zv;
  const int NT = 2048 >> 5;
  gll16(Ahi + ao0, &Ah[0][c0 * 8]); gll16(Ahi + ao1, &Ah[0][c1 * 8]);
  gll16(Alo + ao0, &Al[0][c0 * 8]); gll16(Alo + ao1, &Al[0][c1 * 8]);
  gll16(Bhi + bo0, &Bh[0][c0 * 8]); gll16(Bhi + bo1, &Bh[0][c1 * 8]);
  gll16(Blo + bo0, &Bl[0][c0 * 8]); gll16(Blo + bo1, &Bl[0][c1 * 8]);
  int cur = 0;
  for (int t = 0; t < NT; ++t) {
    __syncthreads();
    if (t + 1 < NT) {
      int ko = (t + 1) << 5;
      gll16(Ahi + ao0 + ko, &Ah[cur ^ 1][c0 * 8]); gll16(Ahi + ao1 + ko, &Ah[cur ^ 1][c1 * 8]);
      gll16(Alo + ao0 + ko, &Al[cur ^ 1][c0 * 8]); gll16(Alo + ao1 + ko, &Al[cur ^ 1][c1 * 8]);
      gll16(Bhi + bo0 + ko, &Bh[cur ^ 1][c0 * 8]); gll16(Bhi + bo1 + ko, &Bh[cur ^ 1][c1 * 8]);
      gll16(Blo + bo0 + ko, &Bl[cur ^ 1][c0 * 8]); gll16(Blo + bo1 + ko, &Bl[cur ^ 1][c1 * 8]);
    }
    bf16x8 ah[4], al[4], bh[4], bl[4];
#pragma unroll
    for (int i = 0; i < 4; i++) {
      ah[i] = *(const bf16x8*)&Ah[cur][(wm + i * 16 + lr) * 32 + fs];
      al[i] = *(const bf16x8*)&Al[cur][(wm + i * 16 + lr) * 32 + fs];
    }
#pragma unroll
    for (int j = 0; j < 4; j++) {
      bh[j] = *(const bf16x8*)&Bh[cur][(wn + j * 16 + lr) * 32 + fs];
      bl[j] = *(const bf16x8*)&Bl[cur][(wn + j * 16 + lr) * 32 + fs];
    }
#pragma unroll
    for (int i = 0; i < 4; i++)
#pragma unroll
      for (int j = 0; j < 4; j++) {
        acc[i][j] = __builtin_amdgcn_mfma_f32_16x16x32_bf16(ah[i], bh[j], acc[i][j], 0, 0, 0);
        acc[i][j] = __builtin_amdgcn_mfma_f32_16x16x32_bf16(ah[i], bl[j], acc[i][j], 0, 0, 0);
        acc[i][j] = __builtin_amdgcn_mfma_f32_16x16x32_bf16(al[i], bh[j], acc[i][j], 0, 0, 0);
      }
    cur ^= 1;
  }
#pragma unroll
  for (int i = 0; i < 4; i++) {
    const int row = m0 + wm + i * 16 + lg * 4;
#pragma unroll
    for (int j = 0; j < 4; j++) {
      const int col = n0 + wn + j * 16 + lr;
#pragma unroll
      for (int r = 0; r < 4; r++)
        C[(size_t)(row + r) * 3072 + col] = acc[i][j][r];
    }
  }
}

// ---------------- GEMM C[M,N] = A[M,K]bf16 * BT[N,K]bf16 (+residual) ----------------
// bounds (256,4): 60 arch + 64 acc = 124 regs <= 128/wave budget at 4 blk/CU;
// LDS 32KB*4 = 128KB <= 160KB. 2-barrier structure hides drain via resident blocks.
template <int MODE>
__launch_bounds__(256, 4)
__global__ void gemm_bt(const u16* __restrict__ A, const u16* __restrict__ BT,
                        float* __restrict__ C, const float* __restrict__ addf,
                        int N, int K) {
  __shared__ __align__(16) u16 Albuf[2][128 * 32];
  __shared__ __align__(16) u16 Blbuf[2][128 * 32];
  const int tid = threadIdx.x;
  const int wid = tid >> 6, lane = tid & 63, lr = lane & 15, lg = lane >> 4;
  const int m0 = blockIdx.x * 128, n0 = blockIdx.y * 128;
  const int wm = (wid >> 1) * 64, wn = (wid & 1) * 64;
  const int c0 = tid, c1 = tid + 256;
  const int ss0 = ((c0 & 3) ^ ((c0 >> 3) & 3)) * 8;
  const int ss1 = ((c1 & 3) ^ ((c1 >> 3) & 3)) * 8;
  const int fs = (lg ^ ((lr >> 1) & 3)) * 8;
  const u16* a0 = A + (size_t)(m0 + (c0 >> 2)) * K + ss0;
  const u16* a1 = A + (size_t)(m0 + (c1 >> 2)) * K + ss1;
  const u16* b0 = BT + (size_t)(n0 + (c0 >> 2)) * K + ss0;
  const u16* b1 = BT + (size_t)(n0 + (c1 >> 2)) * K + ss1;
  f32x4 zv = {0.f, 0.f, 0.f, 0.f};
  f32x4 acc[4][4];
#pragma unroll
  for (int i = 0; i < 4; i++)
#pragma unroll
    for (int j = 0; j < 4; j++) acc[i][j] = zv;
  const int NT = K >> 5;
  gll16(a0, &Albuf[0][c0 * 8]); gll16(a1, &Albuf[0][c1 * 8]);
  gll16(b0, &Blbuf[0][c0 * 8]); gll16(b1, &Blbuf[0][c1 * 8]);
  int cur = 0;
  for (int t = 0; t < NT; ++t) {
    __syncthreads();
    if (t + 1 < NT) {
      int ko = (t + 1) << 5;
      gll16(a0 + ko, &Albuf[cur ^ 1][c0 * 8]); gll16(a1 + ko, &Albuf[cur ^ 1][c1 * 8]);
      gll16(b0 + ko, &Blbuf[cur ^ 1][c0 * 8]); gll16(b1 + ko, &Blbuf[cur ^ 1][c1 * 8]);
    }
    bf16x8 af[4], bf[4];
#pragma unroll
    for (int i = 0; i < 4; i++) af[i] = *(const bf16x8*)&Albuf[cur][(wm + i * 16 + lr) * 32 + fs];
#pragma unroll
    for (int j = 0; j < 4; j++) bf[j] = *(const bf16x8*)&Blbuf[cur][(wn + j * 16 + lr) * 32 + fs];
#pragma unroll
    for (int i = 0; i < 4; i++)
#pragma unroll
      for (int j = 0; j < 4; j++)
        acc[i][j] = __builtin_amdgcn_mfma_f32_16x16x32_bf16(af[i], bf[j], acc[i][j], 0, 0, 0);
    cur ^= 1;
  }
#pragma unroll
  for (int i = 0; i < 4; i++) {
    const int row = m0 + wm + i * 16 + lg * 4;
#pragma unroll
    for (int j = 0; j < 4; j++) {
      const int col = n0 + wn + j * 16 + lr;
#pragma unroll
      for (int r = 0; r < 4; r++) {
        float v = acc[i][j][r];
        if (MODE == 1) v += addf[(size_t)(row + r) * N + col];
        C[(size_t)(row + r) * N + col] = v;
      }
    }
  }
}

// ---------------- RoPE + bf16 hi/lo pack of q/k, bf16 v ----------------
__global__ void k_rope(const int* __restrict__ pos, const float* __restrict__ qkvf,
                       u16* __restrict__ qhi, u16* __restrict__ qlo,
                       u16* __restrict__ khi, u16* __restrict__ klo,
                       u16* __restrict__ vb) {
  __shared__ float invtab[64];
  const int t = blockIdx.x, tid = threadIdx.x;
  if (tid < 64) invtab[tid] = 1.0f / (float)pow(1.0e6, (double)tid / 64.0);
  __syncthreads();
  const float p = (float)pos[t];
  const float* src = qkvf + (size_t)t * 3072;
#pragma unroll
  for (int it = 0; it < 4; ++it) {
    int idx = tid + it * 256;
    int head = idx >> 6, i = idx & 63;
    float ang = p * invtab[i];
    float cc, ssn;
    sincosf(ang, &ssn, &cc);
    float x1 = src[head * 128 + i], x2 = src[head * 128 + i + 64];
    float y1 = x1 * cc - x2 * ssn;
    float y2 = x2 * cc + x1 * ssn;
    u16 h1 = f2b(y1), h2 = f2b(y2);
    size_t o1 = (size_t)t * 2048 + head * 128 + i;
    qhi[o1] = h1;      qlo[o1] = f2b(y1 - b2f(h1));
    qhi[o1 + 64] = h2; qlo[o1 + 64] = f2b(y2 - b2f(h2));
  }
  {
    int head = tid >> 6, i = tid & 63;
    float ang = p * invtab[i];
    float cc, ssn;
    sincosf(ang, &ssn, &cc);
    float x1 = src[2048 + head * 128 + i], x2 = src[2048 + head * 128 + i + 64];
    float y1 = x1 * cc - x2 * ssn;
    float y2 = x2 * cc + x1 * ssn;
    u16 h1 = f2b(y1), h2 = f2b(y2);
    size_t o1 = (size_t)t * 512 + head * 128 + i;
    khi[o1] = h1;      klo[o1] = f2b(y1 - b2f(h1));
    khi[o1 + 64] = h2; klo[o1 + 64] = f2b(y2 - b2f(h2));
  }
#pragma unroll
  for (int u = 0; u < 2; ++u) {
    int ccol = tid + u * 256;
    vb[(size_t)t * 512 + ccol] = f2b(src[2560 + ccol]);
  }
}

// ---------------- tiny f32 helpers for the accurate gate path ----------------
__global__ void k_G(const float* __restrict__ ln2w, const float* __restrict__ gw,
                    float* __restrict__ G) {
  int i = blockIdx.x * 256 + threadIdx.x;   // 2048*8
  G[i] = ln2w[i >> 3] * gw[i];
}
__global__ void k_WG(const float* __restrict__ wo, const float* __restrict__ G,
                     float* __restrict__ WG) {
  int i = blockIdx.x * 256 + threadIdx.x;   // 2048*8
  int r = i >> 3, e = i & 7;
  const float* wr_ = wo + (size_t)r * 2048;
  float s0 = 0, s1 = 0, s2 = 0, s3 = 0;
  for (int c = 0; c < 2048; c += 4) {
    s0 += wr_[c] * G[c * 8 + e];
    s1 += wr_[c + 1] * G[(c + 1) * 8 + e];
    s2 += wr_[c + 2] * G[(c + 2) * 8 + e];
    s3 += wr_[c + 3] * G[(c + 3) * 8 + e];
  }
  WG[i] = (s0 + s1) + (s2 + s3);
}
__global__ void k_resG(const float* __restrict__ resf, const float* __restrict__ G,
                       float* __restrict__ resG) {
  int i = blockIdx.x * 256 + threadIdx.x;   // 2048*8
  int t = i >> 3, e = i & 7;
  const float* rr = resf + (size_t)t * 2048;
  float s0 = 0, s1 = 0, s2 = 0, s3 = 0;
  for (int c = 0; c < 2048; c += 4) {
    s0 += rr[c] * G[c * 8 + e];
    s1 += rr[c + 1] * G[(c + 1) * 8 + e];
    s2 += rr[c + 2] * G[(c + 2) * 8 + e];
    s3 += rr[c + 3] * G[(c + 3) * 8 + e];
  }
  resG[i] = (s0 + s1) + (s2 + s3);
}
__global__ void k_VG(const float* __restrict__ qkvf, const float* __restrict__ WG,
                     float* __restrict__ VG) {
  int i = blockIdx.x * 256 + threadIdx.x;   // 16*2048*8
  int e = i & 7, t = (i >> 3) & 2047, h = i >> 14;
  const float* vr = qkvf + (size_t)t * 3072 + 2560 + (h >> 2) * 128;
  const float* wgr = WG + (size_t)(h * 128) * 8 + e;
  float s = 0;
#pragma unroll 4
  for (int d = 0; d < 128; d++) s += vr[d] * wgr[d * 8];
  VG[i] = s;   // layout [h][t][e]
}

// ---------------- merged flash attention ----------------
__launch_bounds__(256, 2)
__global__ void k_attn2(const u16* __restrict__ qh, const u16* __restrict__ qlo,
                        const u16* __restrict__ kh, const u16* __restrict__ klo,
                        const u16* __restrict__ vb, const float* __restrict__ vg,
                        u16* __restrict__ attnb, float* __restrict__ pvgp) {
  __shared__ __align__(16) u16 Kh[64 * 128];
  __shared__ __align__(16) u16 Kl[64 * 128];
  __shared__ __align__(16) u16 VTl[128 * 64];
  __shared__ __align__(16) u16 Pl[4][16 * 72];
  const int tid = threadIdx.x, wid = tid >> 6, lane = tid & 63, lr = lane & 15, lg = lane >> 4;
  const int h = blockIdx.y, hk = h >> 2, wr = wid * 16;
  f32x4 zv = {0.f, 0.f, 0.f, 0.f};

  for (int half = 0; half < 2; ++half) {
    const int qt = half ? blockIdx.x : 31 - blockIdx.x;   // pair {31-x, x}
    const int q0 = qt * 64;
    float m_[4], l_[4], avg[4][8];
    f32x4 accO[8];
#pragma unroll
    for (int r = 0; r < 4; r++) {
      m_[r] = -3e38f; l_[r] = 0.f;
#pragma unroll
      for (int e = 0; e < 8; e++) avg[r][e] = 0.f;
    }
#pragma unroll
    for (int d = 0; d < 8; d++) accO[d] = zv;
    bf16x8 aqh[4], aql[4];
    {
      const size_t qb = (size_t)(q0 + wr + lr) * 2048 + h * 128 + lg * 8;
#pragma unroll
      for (int kk = 0; kk < 4; kk++) {
        aqh[kk] = *(const bf16x8*)(qh + qb + kk * 32);
        aql[kk] = *(const bf16x8*)(qlo + qb + kk * 32);
      }
    }
    const int nk = qt + 1;
    for (int kt = 0; kt < nk; ++kt) {
      const int s0 = kt * 64;
      __syncthreads();
#pragma unroll
      for (int i = 0; i < 4; i++) {
        int c = tid + i * 256;
        int s = c >> 4, b = (c & 15) * 8;
        size_t go = (size_t)(s0 + s) * 512 + hk * 128 + (b ^ ((s & 7) << 3));
        gll16(kh + go, &Kh[c * 8]);
        gll16(klo + go, &Kl[c * 8]);
      }
      {
        int s = tid >> 2;
        const u16* vsrc = vb + (size_t)(s0 + s) * 512 + hk * 128 + (tid & 3) * 32;
#pragma unroll
        for (int u = 0; u < 4; u++) {
          uint4 wv = *(const uint4*)(vsrc + u * 8);
          const u16* tp = (const u16*)&wv;
          int d0b = (tid & 3) * 32 + u * 8;
          int scol = s ^ (((d0b >> 3) & 7) << 3);
#pragma unroll
          for (int ii = 0; ii < 8; ii++) VTl[(d0b + ii) * 64 + scol] = tp[ii];
        }
      }
      float vgr[4][8];
#pragma unroll
      for (int ct = 0; ct < 4; ct++) {
        const float* vp = vg + ((size_t)h * 2048 + s0 + ct * 16 + lr) * 8;
        float4 u0 = *(const float4*)vp;
        float4 u1 = *(const float4*)(vp + 4);
        vgr[ct][0] = u0.x; vgr[ct][1] = u0.y; vgr[ct][2] = u0.z; vgr[ct][3] = u0.w;
        vgr[ct][4] = u1.x; vgr[ct][5] = u1.y; vgr[ct][6] = u1.z; vgr[ct][7] = u1.w;
      }
      __syncthreads();
      f32x4 accS[4];
#pragma unroll
      for (int ct = 0; ct < 4; ct++) accS[ct] = zv;
      __builtin_amdgcn_s_setprio(1);
#pragma unroll
      for (int kk = 0; kk < 4; kk++) {
#pragma unroll
        for (int ct = 0; ct < 4; ct++) {
          int off = (ct * 16 + lr) * 128 + ((kk * 32 + lg * 8) ^ ((lr & 7) << 3));
          bf16x8 bh = *(const bf16x8*)&Kh[off];
          bf16x8 bl = *(const bf16x8*)&Kl[off];
          accS[ct] = __builtin_amdgcn_mfma_f32_16x16x32_bf16(aqh[kk], bh, accS[ct], 0, 0, 0);
          accS[ct] = __builtin_amdgcn_mfma_f32_16x16x32_bf16(aqh[kk], bl, accS[ct], 0, 0, 0);
          accS[ct] = __builtin_amdgcn_mfma_f32_16x16x32_bf16(aql[kk], bh, accS[ct], 0, 0, 0);
        }
      }
      __builtin_amdgcn_s_setprio(0);
      const bool diag = (kt == qt);
      float alpha[4];
#pragma unroll
      for (int r = 0; r < 4; r++) {
        float sv[4];
        float mx = -3e38f;
#pragma unroll
        for (int ct = 0; ct < 4; ct++) {
          float sc = accS[ct][r] * 0.08838834764831845f;
          if (diag) {
            int col = ct * 16 + lr;
            int row = wr + lg * 4 + r;
            if (col > row) sc = -3e38f;
          }
          sv[ct] = sc; mx = fmaxf(mx, sc);
        }
#pragma unroll
        for (int m2 = 1; m2 < 16; m2 <<= 1) mx = fmaxf(mx, __shfl_xor(mx, m2));
        float mnew = fmaxf(m_[r], mx);
        float a = expf(m_[r] - mnew);
        float pv[4];
        float rs = 0.f;
#pragma unroll
        for (int ct = 0; ct < 4; ct++) { pv[ct] = expf(sv[ct] - mnew); rs += pv[ct]; }
#pragma unroll
        for (int m2 = 1; m2 < 16; m2 <<= 1) rs += __shfl_xor(rs, m2);
        l_[r] = l_[r] * a + rs;
        m_[r] = mnew;
        alpha[r] = a;
#pragma unroll
        for (int e = 0; e < 8; e++) avg[r][e] *= a;
#pragma unroll
        for (int ct = 0; ct < 4; ct++) {
          Pl[wid][(lg * 4 + r) * 72 + ct * 16 + lr] = f2b(pv[ct]);
#pragma unroll
          for (int e = 0; e < 8; e++) avg[r][e] += pv[ct] * vgr[ct][e];
        }
      }
#pragma unroll
      for (int d = 0; d < 8; d++)
#pragma unroll
        for (int r = 0; r < 4; r++) accO[d][r] *= alpha[r];
      // no barrier: Pl[wid] same-wave; VTl covered by post-staging barrier
      __builtin_amdgcn_s_setprio(1);
#pragma unroll
      for (int ks = 0; ks < 2; ks++) {
        bf16x8 ap = *(const bf16x8*)&Pl[wid][lr * 72 + ks * 32 + lg * 8];
#pragma unroll
        for (int d0 = 0; d0 < 8; d0++) {
          int d = d0 * 16 + lr;
          int scol = (ks * 32 + lg * 8) ^ (((d >> 3) & 7) << 3);
          bf16x8 bv = *(const bf16x8*)&VTl[d * 64 + scol];
          accO[d0] = __builtin_amdgcn_mfma_f32_16x16x32_bf16(ap, bv, accO[d0], 0, 0, 0);
        }
      }
      __builtin_amdgcn_s_setprio(0);
    }
#pragma unroll
    for (int d0 = 0; d0 < 8; d0++)
#pragma unroll
      for (int r = 0; r < 4; r++) {
        float v = accO[d0][r] / l_[r];
        attnb[(size_t)(q0 + wr + lg * 4 + r) * 2048 + h * 128 + d0 * 16 + lr] = f2b(v);
      }
#pragma unroll
    for (int m2 = 1; m2 < 16; m2 <<= 1)
#pragma unroll
      for (int r = 0; r < 4; r++)
#pragma unroll
        for (int e = 0; e < 8; e++) avg[r][e] += __shfl_xor(avg[r][e], m2);
#pragma unroll
    for (int r = 0; r < 4; r++) {
      int t = q0 + wr + lg * 4 + r;
      float inv = 1.f / l_[r];
#pragma unroll
      for (int e = 0; e < 8; e++)
        if (lr == e) pvgp[((size_t)h * 2048 + t) * 8 + e] = avg[r][e] * inv;
    }
  }
}

// ---------------- RMSNorm(ln2) + accurate-logit gate + top2 routing ----------------
__global__ void k_ln2gate(const float* __restrict__ res2, const float* __restrict__ w,
                          const float* __restrict__ resG, const float* __restrict__ pvgp,
                          u16* __restrict__ h2b,
                          int* __restrict__ cnt, int* __restrict__ tok,
                          float* __restrict__ wgt, int* __restrict__ jid) {
  const int t = blockIdx.x, tid = threadIdx.x, lane = tid & 63, wid = tid >> 6;
  __shared__ float red[4];
  const size_t base = (size_t)t * Hh;
  float4 r1 = *(const float4*)(res2 + base + tid * 4);
  float4 r2 = *(const float4*)(res2 + base + 1024 + tid * 4);
  float ss = r1.x*r1.x + r1.y*r1.y + r1.z*r1.z + r1.w*r1.w
           + r2.x*r2.x + r2.y*r2.y + r2.z*r2.z + r2.w*r2.w;
#pragma unroll
  for (int m = 1; m < 64; m <<= 1) ss += __shfl_xor(ss, m);
  if (lane == 0) red[wid] = ss;
  __syncthreads();
  float tot = red[0] + red[1] + red[2] + red[3];
  float rstd = rsqrtf(tot * (1.f / Hh) + 1e-5f);
  float4 w1v = *(const float4*)(w + tid * 4);
  float4 w2v = *(const float4*)(w + 1024 + tid * 4);
  ushort4 o1, o2;
  o1.x = f2b(r1.x * rstd * w1v.x); o1.y = f2b(r1.y * rstd * w1v.y);
  o1.z = f2b(r1.z * rstd * w1v.z); o1.w = f2b(r1.w * rstd * w1v.w);
  o2.x = f2b(r2.x * rstd * w2v.x); o2.y = f2b(r2.y * rstd * w2v.y);
  o2.z = f2b(r2.z * rstd * w2v.z); o2.w = f2b(r2.w * rstd * w2v.w);
  *(ushort4*)(h2b + base + tid * 4) = o1;
  *(ushort4*)(h2b + base + 1024 + tid * 4) = o2;
  if (tid == 0) {
    float lg8[8];
#pragma unroll
    for (int e = 0; e < 8; e++) {
      float s = resG[t * 8 + e];
      for (int hh = 0; hh < 16; hh++) s += pvgp[((size_t)hh * 2048 + t) * 8 + e];
      lg8[e] = s * rstd;
    }
    float mx = lg8[0];
#pragma unroll
    for (int e = 1; e < 8; e++) mx = fmaxf(mx, lg8[e]);
    float ex[8];
#pragma unroll
    for (int e = 0; e < 8; e++) ex[e] = expf(lg8[e] - mx);
    int i1 = 0; float v1 = ex[0];
#pragma unroll
    for (int e = 1; e < 8; e++) if (ex[e] > v1) { v1 = ex[e]; i1 = e; }
    int i2 = -1; float v2 = -1.f;
#pragma unroll
    for (int e = 0; e < 8; e++) if (e != i1 && ex[e] > v2) { v2 = ex[e]; i2 = e; }
    float inv = 1.f / (v1 + v2);
    int s1 = atomicAdd(&cnt[i1], 1);
    tok[i1 * 2048 + s1] = t; wgt[i1 * 2048 + s1] = v1 * inv; jid[i1 * 2048 + s1] = 0;
    int s2 = atomicAdd(&cnt[i2], 1);
    tok[i2 * 2048 + s2] = t; wgt[i2 * 2048 + s2] = v2 * inv; jid[i2 * 2048 + s2] = 1;
  }
}

// ---------------- MoE GEMM1, split into two single-B passes ----------------
template <int PHASE>
__launch_bounds__(256, 4)
__global__ void gemm_m13(const u16* __restrict__ h2b, const u16* __restrict__ wT,
                         u16* __restrict__ gbuf, float* __restrict__ x1,
                         const int* __restrict__ cnt, const int* __restrict__ tok) {
  const int e = blockIdx.z;
  const int cnt_e = cnt[e];
  const int m0 = blockIdx.y * 128;
  if (m0 >= cnt_e) return;
  int gb = 0;
#pragma unroll
  for (int i = 0; i < 8; i++) if (i < e) gb += cnt[i];
  __shared__ __align__(16) u16 Al[2][128 * 32];
  __shared__ __align__(16) u16 Bl[2][128 * 32];
  const int tid = threadIdx.x;
  const int wid = tid >> 6, lane = tid & 63, lr = lane & 15, lg = lane >> 4;
  const int n0 = blockIdx.x * 128;
  const int wm = (wid >> 1) * 64, wn = (wid & 1) * 64;
  const int c0 = tid, c1 = tid + 256;
  const int ss0 = ((c0 & 3) ^ ((c0 >> 3) & 3)) * 8;
  const int ss1 = ((c1 & 3) ^ ((c1 >> 3) & 3)) * 8;
  const int fs = (lg ^ ((lr >> 1) & 3)) * 8;
  int r0 = m0 + (c0 >> 2); if (r0 > cnt_e - 1) r0 = cnt_e - 1;
  int r1 = m0 + (c1 >> 2); if (r1 > cnt_e - 1) r1 = cnt_e - 1;
  const int tk0 = tok[e * 2048 + r0], tk1 = tok[e * 2048 + r1];
  const u16* a0 = h2b + (size_t)tk0 * 2048 + ss0;
  const u16* a1 = h2b + (size_t)tk1 * 2048 + ss1;
  const u16* b0 = wT + (size_t)e * DFFd * 2048 + (size_t)(n0 + (c0 >> 2)) * 2048 + ss0;
  const u16* b1 = wT + (size_t)e * DFFd * 2048 + (size_t)(n0 + (c1 >> 2)) * 2048 + ss1;
  f32x4 zv = {0.f, 0.f, 0.f, 0.f};
  f32x4 acc[4][4];
#pragma unroll
  for (int i = 0; i < 4; i++)
#pragma unroll
    for (int j = 0; j < 4; j++) acc[i][j] = zv;
  const int NT = 2048 >> 5;
  gll16(a0, &Al[0][c0 * 8]); gll16(a1, &Al[0][c1 * 8]);
  gll16(b0, &Bl[0][c0 * 8]); gll16(b1, &Bl[0][c1 * 8]);
  int cur = 0;
  for (int t = 0; t < NT; ++t) {
    __syncthreads();
    if (t + 1 < NT) {
      int ko = (t + 1) << 5;
      gll16(a0 + ko, &Al[cur ^ 1][c0 * 8]); gll16(a1 + ko, &Al[cur ^ 1][c1 * 8]);
      gll16(b0 + ko, &Bl[cur ^ 1][c0 * 8]); gll16(b1 + ko, &Bl[cur ^ 1][c1 * 8]);
    }
    bf16x8 af[4], bf[4];
#pragma unroll
    for (int i = 0; i < 4; i++) af[i] = *(const bf16x8*)&Al[cur][(wm + i * 16 + lr) * 32 + fs];
#pragma unroll
    for (int j = 0; j < 4; j++) bf[j] = *(const bf16x8*)&Bl[cur][(wn + j * 16 + lr) * 32 + fs];
#pragma unroll
    for (int i = 0; i < 4; i++)
#pragma unroll
      for (int j = 0; j < 4; j++)
        acc[i][j] = __builtin_amdgcn_mfma_f32_16x16x32_bf16(af[i], bf[j], acc[i][j], 0, 0, 0);
    cur ^= 1;
  }
#pragma unroll
  for (int i = 0; i < 4; i++) {
    const int slotb = m0 + wm + i * 16 + lg * 4;
#pragma unroll
    for (int j = 0; j < 4; j++) {
      const int col = n0 + wn + j * 16 + lr;
#pragma unroll
      for (int r = 0; r < 4; r++) {
        int slot = slotb + r;
        if (slot < cnt_e) {
          size_t o = (size_t)(gb + slot) * DFFd + col;
          if (PHASE == 0) {
            x1[o] = acc[i][j][r];
          } else {
            float xv = x1[o];
            float g = xv / (1.f + __expf(-xv)) * acc[i][j][r];
            gbuf[o] = f2b(g);
          }
        }
      }
    }
  }
}

// ---------------- MoE GEMM2: out_j[token] = w * (g @ w2) ----------------
__launch_bounds__(256, 4)
__global__ void gemm2k(const u16* __restrict__ gbuf, const u16* __restrict__ w2T,
                       float* __restrict__ outk, const int* __restrict__ cnt,
                       const int* __restrict__ tok, const float* __restrict__ wgt,
                       const int* __restrict__ jid) {
  const int e = blockIdx.z;
  const int cnt_e = cnt[e];
  const int m0 = blockIdx.y * 128;
  if (m0 >= cnt_e) return;
  int gb = 0;
#pragma unroll
  for (int i = 0; i < 8; i++) if (i < e) gb += cnt[i];
  __shared__ __align__(16) u16 Al[2][128 * 32];
  __shared__ __align__(16) u16 Bl[2][128 * 32];
  const int tid = threadIdx.x;
  const int wid = tid >> 6, lane = tid & 63, lr = lane & 15, lg = lane >> 4;
  const int n0 = blockIdx.x * 128;
  const int wm = (wid >> 1) * 64, wn = (wid & 1) * 64;
  const int c0 = tid, c1 = tid + 256;
  const int ss0 = ((c0 & 3) ^ ((c0 >> 3) & 3)) * 8;
  const int ss1 = ((c1 & 3) ^ ((c1 >> 3) & 3)) * 8;
  const int fs = (lg ^ ((lr >> 1) & 3)) * 8;
  const u16* A = gbuf + (size_t)gb * DFFd;
  const u16* a0 = A + (size_t)(m0 + (c0 >> 2)) * DFFd + ss0;
  const u16* a1 = A + (size_t)(m0 + (c1 >> 2)) * DFFd + ss1;
  const u16* b0 = w2T + (size_t)e * 2048 * DFFd + (size_t)(n0 + (c0 >> 2)) * DFFd + ss0;
  const u16* b1 = w2T + (size_t)e * 2048 * DFFd + (size_t)(n0 + (c1 >> 2)) * DFFd + ss1;
  f32x4 zv = {0.f, 0.f, 0.f, 0.f};
  f32x4 acc[4][4];
#pragma unroll
  for (int i = 0; i < 4; i++)
#pragma unroll
    for (int j = 0; j < 4; j++) acc[i][j] = zv;
  const int NT = DFFd >> 5;
  gll16(a0, &Al[0][c0 * 8]); gll16(a1, &Al[0][c1 * 8]);
  gll16(b0, &Bl[0][c0 * 8]); gll16(b1, &Bl[0][c1 * 8]);
  int cur = 0;
  for (int t = 0; t < NT; ++t) {
    __syncthreads();
    if (t + 1 < NT) {
      int ko = (t + 1) << 5;
      gll16(a0 + ko, &Al[cur ^ 1][c0 * 8]); gll16(a1 + ko, &Al[cur ^ 1][c1 * 8]);
      gll16(b0 + ko, &Bl[cur ^ 1][c0 * 8]); gll16(b1 + ko, &Bl[cur ^ 1][c1 * 8]);
    }
    bf16x8 af[4], bf[4];
#pragma unroll
    for (int i = 0; i < 4; i++) af[i] = *(const bf16x8*)&Al[cur][(wm + i * 16 + lr) * 32 + fs];
#pragma unroll
    for (int j = 0; j < 4; j++) bf[j] = *(const bf16x8*)&Bl[cur][(wn + j * 16 + lr) * 32 + fs];
#pragma unroll
    for (int i = 0; i < 4; i++)
#pragma unroll
      for (int j = 0; j < 4; j++)
        acc[i][j] = __builtin_amdgcn_mfma_f32_16x16x32_bf16(af[i], bf[j], acc[i][j], 0, 0, 0);
    cur ^= 1;
  }
#pragma unroll
  for (int i = 0; i < 4; i++) {
    const int slotb = m0 + wm + i * 16 + lg * 4;
#pragma unroll
    for (int r = 0; r < 4; r++) {
      int slot = slotb + r;
      if (slot < cnt_e) {
        int tkn = tok[e * 2048 + slot];
        float wv = wgt[e * 2048 + slot];
        int jj = jid[e * 2048 + slot];
        float* orow = outk + (size_t)jj * ((size_t)Tt * Hh) + (size_t)tkn * Hh;
#pragma unroll
        for (int j = 0; j < 4; j++) {
          const int col = n0 + wn + j * 16 + lr;
          orow[col] = wv * acc[i][j][r];
        }
      }
    }
  }
}

__global__ void k_zero(int* cnt) { if (threadIdx.x < 8) cnt[threadIdx.x] = 0; }

__global__ void k_combine(const float* __restrict__ outk, float* __restrict__ dout) {
  size_t i = ((size_t)blockIdx.x * 256 + threadIdx.x) * 4;
  float4 a = *(const float4*)(outk + i);
  float4 b = *(const float4*)(outk + (size_t)Tt * Hh + i);
  float4 o = {a.x + b.x, a.y + b.y, a.z + b.z, a.w + b.w};
  *(float4*)(dout + i) = o;
}

extern "C" void kernel_launch(void* const* d_in, const int* in_sizes, int n_in,
                              void* d_out, int out_size, void* d_ws, size_t ws_size,
                              hipStream_t stream) {
  const int*   positions = (const int*)d_in[0];
  const float* hs    = (const float*)d_in[1];
  const float* resid = (const float*)d_in[2];
  const float* ln1w  = (const float*)d_in[3];
  const float* ln2w  = (const float*)d_in[4];
  const float* wq    = (const float*)d_in[5];
  const float* wk    = (const float*)d_in[6];
  const float* wv    = (const float*)d_in[7];
  const float* wo    = (const float*)d_in[8];
  const float* gatew = (const float*)d_in[9];
  const float* w1    = (const float*)d_in[10];
  const float* w3    = (const float*)d_in[11];
  const float* w2    = (const float*)d_in[12];
  float* dout = (float*)d_out;
  float* res2 = dout + (size_t)Tt * Hh;

  char* wp = (char*)d_ws;
  auto take = [&](size_t bytes) -> void* {
    void* p = (void*)wp;
    wp += (bytes + 255) & ~(size_t)255;
    return p;
  };
  u16*   qkvT  = (u16*)  take((size_t)3072 * 2048 * 2);
  u16*   qkvTl = (u16*)  take((size_t)3072 * 2048 * 2);
  u16*   woT   = (u16*)  take((size_t)2048 * 2048 * 2);
  u16*   w1T   = (u16*)  take((size_t)8 * 4096 * 2048 * 2);
  u16*   w3T   = (u16*)  take((size_t)8 * 4096 * 2048 * 2);
  u16*   w2T   = (u16*)  take((size_t)8 * 2048 * 4096 * 2);
  float* resf  = (float*)take((size_t)Tt * Hh * 4);            // 16 MB ┐
  u16*   hb    = (u16*)  take((size_t)Tt * Hh * 2);            //  8 MB │ dead after attn/wo-GEMM;
  u16*   hblo  = (u16*)  take((size_t)Tt * Hh * 2);            //  8 MB │ reused as x1 scratch
  float* qkvf  = (float*)take((size_t)Tt * 3072 * 4);          // 24 MB │ (4096*4096*4 = 64 MB,
  u16*   qhi   = (u16*)  take((size_t)Tt * 2048 * 2);          //  8 MB ┘  exactly this span)
  u16*   qlo   = (u16*)  take((size_t)Tt * 2048 * 2);
  u16*   khi   = (u16*)  take((size_t)Tt * 512 * 2);
  u16*   klo   = (u16*)  take((size_t)Tt * 512 * 2);
  u16*   vb2   = (u16*)  take((size_t)Tt * 512 * 2);
  u16*   attnb = (u16*)  take((size_t)Tt * 2048 * 2);
  u16*   h2b   = (u16*)  take((size_t)Tt * Hh * 2);
  u16*   gbuf  = (u16*)  take((size_t)(4096 + 128) * 4096 * 2);
  float* outk  = (float*)take((size_t)2 * Tt * Hh * 4);
  float* Gb    = (float*)take((size_t)2048 * 8 * 4);
  float* WGb   = (float*)take((size_t)2048 * 8 * 4);
  float* resGb = (float*)take((size_t)Tt * 8 * 4);
  float* VGb   = (float*)take((size_t)16 * Tt * 8 * 4);
  float* pvgp  = (float*)take((size_t)16 * Tt * 8 * 4);
  int*   tok   = (int*)  take((size_t)8 * 2048 * 4);
  float* wgt   = (float*)take((size_t)8 * 2048 * 4);
  int*   jid   = (int*)  take((size_t)8 * 2048 * 4);
  int*   cnt   = (int*)  take(64);
  if ((size_t)(wp - (char*)d_ws) > ws_size) return;
  float* x1buf = resf;

  k_zero<<<1, 64, 0, stream>>>(cnt);
  k_addnorm<<<Tt, 256, 0, stream>>>(hs, resid, ln1w, resf, hb, hblo);
  k_transpose2_64<<<dim3(32, 32, 1), 256, 0, stream>>>(wq, qkvT, qkvTl, 2048, 2048);
  k_transpose2_64<<<dim3(32, 8, 1), 256, 0, stream>>>(wk, qkvT + (size_t)2048 * 2048,
                                                      qkvTl + (size_t)2048 * 2048, 2048, 512);
  k_transpose2_64<<<dim3(32, 8, 1), 256, 0, stream>>>(wv, qkvT + (size_t)2560 * 2048,
                                                      qkvTl + (size_t)2560 * 2048, 2048, 512);
  k_transpose64<<<dim3(32, 32, 1), 256, 0, stream>>>(wo, woT, 2048, 2048);
  k_transpose64<<<dim3(32, 64, 8), 256, 0, stream>>>(w1, w1T, 2048, 4096);
  k_transpose64<<<dim3(32, 64, 8), 256, 0, stream>>>(w3, w3T, 2048, 4096);
  k_transpose64<<<dim3(64, 32, 8), 256, 0, stream>>>(w2, w2T, 4096, 2048);
  k_G<<<64, 256, 0, stream>>>(ln2w, gatew, Gb);
  k_WG<<<64, 256, 0, stream>>>(wo, Gb, WGb);
  k_resG<<<64, 256, 0, stream>>>(resf, Gb, resGb);
  gemm_qkv<<<dim3(16, 24, 1), 256, 0, stream>>>(hb, hblo, qkvT, qkvTl, qkvf);
  k_rope<<<Tt, 256, 0, stream>>>(positions, qkvf, qhi, qlo, khi, klo, vb2);
  k_VG<<<1024, 256, 0, stream>>>(qkvf, WGb, VGb);
  k_attn2<<<dim3(16, 16, 1), 256, 0, stream>>>(qhi, qlo, khi, klo, vb2, VGb, attnb, pvgp);
  gemm_bt<1><<<dim3(16, 16, 1), 256, 0, stream>>>(attnb, woT, res2, resf, 2048, 2048);
  k_ln2gate<<<Tt, 256, 0, stream>>>(res2, ln2w, resGb, pvgp, h2b, cnt, tok, wgt, jid);
  gemm_m13<0><<<dim3(32, 16, 8), 256, 0, stream>>>(h2b, w1T, gbuf, x1buf, cnt, tok);
  gemm_m13<1><<<dim3(32, 16, 8), 256, 0, stream>>>(h2b, w3T, gbuf, x1buf, cnt, tok);
  gemm2k<<<dim3(16, 16, 8), 256, 0, stream>>>(gbuf, w2T, outk, cnt, tok, wgt, jid);
  k_combine<<<4096, 256, 0, stream>>>(outk, dout);
}

// Round 4
// 1144.647 us; speedup vs baseline: 1.1956x; 1.0793x over previous
//
#include <hip/hip_runtime.h>
#include <math.h>

typedef unsigned short u16;
typedef __attribute__((ext_vector_type(8))) short bf16x8;
typedef __attribute__((ext_vector_type(4))) float f32x4;

#define DI __device__ __forceinline__

constexpr int Tt  = 2048;   // tokens
constexpr int Hh  = 2048;   // hidden
constexpr int DFFd = 4096;  // expert ffn dim

DI u16 f2b(float f) {
  union { float f; unsigned u; } x; x.f = f;
  unsigned r = x.u + 0x7fffu + ((x.u >> 16) & 1u);
  return (u16)(r >> 16);
}
DI float b2f(u16 h) {
  union { unsigned u; float f; } x; x.u = ((unsigned)h) << 16; return x.f;
}
DI void gll16(const void* g, void* l) {
  __builtin_amdgcn_global_load_lds((const __attribute__((address_space(1))) unsigned int*)g,
                                   (__attribute__((address_space(3))) unsigned int*)l, 16, 0, 0);
}

// ---------------- fused add + RMSNorm (ln1), with hi/lo bf16 split ----------------
__global__ void k_addnorm(const float* __restrict__ hs, const float* __restrict__ resid,
                          const float* __restrict__ w, float* __restrict__ resf,
                          u16* __restrict__ hb, u16* __restrict__ hblo) {
  const int t = blockIdx.x, tid = threadIdx.x, lane = tid & 63, wid = tid >> 6;
  __shared__ float red[4];
  const size_t base = (size_t)t * Hh;
  float4 a = *(const float4*)(hs + base + tid * 4);
  float4 b = *(const float4*)(resid + base + tid * 4);
  float4 c = *(const float4*)(hs + base + 1024 + tid * 4);
  float4 d = *(const float4*)(resid + base + 1024 + tid * 4);
  float4 r1 = {a.x + b.x, a.y + b.y, a.z + b.z, a.w + b.w};
  float4 r2 = {c.x + d.x, c.y + d.y, c.z + d.z, c.w + d.w};
  *(float4*)(resf + base + tid * 4) = r1;
  *(float4*)(resf + base + 1024 + tid * 4) = r2;
  float ss = r1.x*r1.x + r1.y*r1.y + r1.z*r1.z + r1.w*r1.w
           + r2.x*r2.x + r2.y*r2.y + r2.z*r2.z + r2.w*r2.w;
#pragma unroll
  for (int m = 1; m < 64; m <<= 1) ss += __shfl_xor(ss, m);
  if (lane == 0) red[wid] = ss;
  __syncthreads();
  float tot = red[0] + red[1] + red[2] + red[3];
  float rstd = rsqrtf(tot * (1.f / Hh) + 1e-5f);
  float4 w1v = *(const float4*)(w + tid * 4);
  float4 w2v = *(const float4*)(w + 1024 + tid * 4);
  float hv[8];
  hv[0] = r1.x * rstd * w1v.x; hv[1] = r1.y * rstd * w1v.y;
  hv[2] = r1.z * rstd * w1v.z; hv[3] = r1.w * rstd * w1v.w;
  hv[4] = r2.x * rstd * w2v.x; hv[5] = r2.y * rstd * w2v.y;
  hv[6] = r2.z * rstd * w2v.z; hv[7] = r2.w * rstd * w2v.w;
  ushort4 o1, o2, l1, l2;
  u16 h;
  h = f2b(hv[0]); o1.x = h; l1.x = f2b(hv[0] - b2f(h));
  h = f2b(hv[1]); o1.y = h; l1.y = f2b(hv[1] - b2f(h));
  h = f2b(hv[2]); o1.z = h; l1.z = f2b(hv[2] - b2f(h));
  h = f2b(hv[3]); o1.w = h; l1.w = f2b(hv[3] - b2f(h));
  h = f2b(hv[4]); o2.x = h; l2.x = f2b(hv[4] - b2f(h));
  h = f2b(hv[5]); o2.y = h; l2.y = f2b(hv[5] - b2f(h));
  h = f2b(hv[6]); o2.z = h; l2.z = f2b(hv[6] - b2f(h));
  h = f2b(hv[7]); o2.w = h; l2.w = f2b(hv[7] - b2f(h));
  *(ushort4*)(hb + base + tid * 4) = o1;
  *(ushort4*)(hb + base + 1024 + tid * 4) = o2;
  *(ushort4*)(hblo + base + tid * 4) = l1;
  *(ushort4*)(hblo + base + 1024 + tid * 4) = l2;
}

// ---------------- transpose f32 [K][N] -> bf16 [N][K], 64x64 tiles ----------------
__global__ void k_transpose64(const float* __restrict__ src, u16* __restrict__ dst,
                              int K, int N) {
  size_t zo = (size_t)blockIdx.z * K * N;
  src += zo; dst += zo;
  __shared__ float tl[64][65];
  const int t = threadIdx.x;
  const int k0 = blockIdx.x * 64, n0 = blockIdx.y * 64;
  int r = t >> 4, c = (t & 15) * 4;
#pragma unroll
  for (int u = 0; u < 4; u++) {
    float4 v = *(const float4*)(src + (size_t)(k0 + r + u * 16) * N + n0 + c);
    tl[r + u * 16][c] = v.x; tl[r + u * 16][c + 1] = v.y;
    tl[r + u * 16][c + 2] = v.z; tl[r + u * 16][c + 3] = v.w;
  }
  __syncthreads();
  int n = t >> 2, kc = (t & 3) * 16;
  __align__(16) u16 tmp[16];
#pragma unroll
  for (int i = 0; i < 16; i++) tmp[i] = f2b(tl[kc + i][n]);
  uint4* dp = (uint4*)(dst + (size_t)(n0 + n) * K + k0 + kc);
  dp[0] = ((uint4*)tmp)[0];
  dp[1] = ((uint4*)tmp)[1];
}

// ---------------- transpose f32 [K][N] -> bf16 hi/lo [N][K], 64x64 tiles ----------------
__global__ void k_transpose2_64(const float* __restrict__ src, u16* __restrict__ dhi,
                                u16* __restrict__ dlo, int K, int N) {
  __shared__ float tl[64][65];
  const int t = threadIdx.x;
  const int k0 = blockIdx.x * 64, n0 = blockIdx.y * 64;
  int r = t >> 4, c = (t & 15) * 4;
#pragma unroll
  for (int u = 0; u < 4; u++) {
    float4 v = *(const float4*)(src + (size_t)(k0 + r + u * 16) * N + n0 + c);
    tl[r + u * 16][c] = v.x; tl[r + u * 16][c + 1] = v.y;
    tl[r + u * 16][c + 2] = v.z; tl[r + u * 16][c + 3] = v.w;
  }
  __syncthreads();
  int n = t >> 2, kc = (t & 3) * 16;
  __align__(16) u16 th[16], tlo[16];
#pragma unroll
  for (int i = 0; i < 16; i++) {
    float x = tl[kc + i][n];
    u16 hx = f2b(x);
    th[i] = hx; tlo[i] = f2b(x - b2f(hx));
  }
  uint4* dph = (uint4*)(dhi + (size_t)(n0 + n) * K + k0 + kc);
  dph[0] = ((uint4*)th)[0]; dph[1] = ((uint4*)th)[1];
  uint4* dpl = (uint4*)(dlo + (size_t)(n0 + n) * K + k0 + kc);
  dpl[0] = ((uint4*)tlo)[0]; dpl[1] = ((uint4*)tlo)[1];
}

// ---------------- split-bf16 GEMM: C[M,3072] = (Ahi+Alo)[M,2048] * (Bhi+Blo)^T ----------------
__launch_bounds__(256, 2)
__global__ void gemm_qkv(const u16* __restrict__ Ahi, const u16* __restrict__ Alo,
                         const u16* __restrict__ Bhi, const u16* __restrict__ Blo,
                         float* __restrict__ C) {
  __shared__ __align__(16) u16 Ah[2][128 * 32];
  __shared__ __align__(16) u16 Al[2][128 * 32];
  __shared__ __align__(16) u16 Bh[2][128 * 32];
  __shared__ __align__(16) u16 Bl[2][128 * 32];
  const int tid = threadIdx.x;
  const int wid = tid >> 6, lane = tid & 63, lr = lane & 15, lg = lane >> 4;
  const int m0 = blockIdx.x * 128, n0 = blockIdx.y * 128;
  const int wm = (wid >> 1) * 64, wn = (wid & 1) * 64;
  const int c0 = tid, c1 = tid + 256;
  const int ss0 = ((c0 & 3) ^ ((c0 >> 3) & 3)) * 8;
  const int ss1 = ((c1 & 3) ^ ((c1 >> 3) & 3)) * 8;
  const int fs = (lg ^ ((lr >> 1) & 3)) * 8;
  const size_t ao0 = (size_t)(m0 + (c0 >> 2)) * 2048 + ss0;
  const size_t ao1 = (size_t)(m0 + (c1 >> 2)) * 2048 + ss1;
  const size_t bo0 = (size_t)(n0 + (c0 >> 2)) * 2048 + ss0;
  const size_t bo1 = (size_t)(n0 + (c1 >> 2)) * 2048 + ss1;
  f32x4 zv = {0.f, 0.f, 0.f, 0.f};
  f32x4 acc[4][4];
#pragma unroll
  for (int i = 0; i < 4; i++)
#pragma unroll
    for (int j = 0; j < 4; j++) acc[i][j] = zv;
  const int NT = 2048 >> 5;
  gll16(Ahi + ao0, &Ah[0][c0 * 8]); gll16(Ahi + ao1, &Ah[0][c1 * 8]);
  gll16(Alo + ao0, &Al[0][c0 * 8]); gll16(Alo + ao1, &Al[0][c1 * 8]);
  gll16(Bhi + bo0, &Bh[0][c0 * 8]); gll16(Bhi + bo1, &Bh[0][c1 * 8]);
  gll16(Blo + bo0, &Bl[0][c0 * 8]); gll16(Blo + bo1, &Bl[0][c1 * 8]);
  int cur = 0;
  for (int t = 0; t < NT; ++t) {
    __syncthreads();
    if (t + 1 < NT) {
      int ko = (t + 1) << 5;
      gll16(Ahi + ao0 + ko, &Ah[cur ^ 1][c0 * 8]); gll16(Ahi + ao1 + ko, &Ah[cur ^ 1][c1 * 8]);
      gll16(Alo + ao0 + ko, &Al[cur ^ 1][c0 * 8]); gll16(Alo + ao1 + ko, &Al[cur ^ 1][c1 * 8]);
      gll16(Bhi + bo0 + ko, &Bh[cur ^ 1][c0 * 8]); gll16(Bhi + bo1 + ko, &Bh[cur ^ 1][c1 * 8]);
      gll16(Blo + bo0 + ko, &Bl[cur ^ 1][c0 * 8]); gll16(Blo + bo1 + ko, &Bl[cur ^ 1][c1 * 8]);
    }
    bf16x8 ah[4], al[4], bh[4], bl[4];
#pragma unroll
    for (int i = 0; i < 4; i++) {
      ah[i] = *(const bf16x8*)&Ah[cur][(wm + i * 16 + lr) * 32 + fs];
      al[i] = *(const bf16x8*)&Al[cur][(wm + i * 16 + lr) * 32 + fs];
    }
#pragma unroll
    for (int j = 0; j < 4; j++) {
      bh[j] = *(const bf16x8*)&Bh[cur][(wn + j * 16 + lr) * 32 + fs];
      bl[j] = *(const bf16x8*)&Bl[cur][(wn + j * 16 + lr) * 32 + fs];
    }
#pragma unroll
    for (int i = 0; i < 4; i++)
#pragma unroll
      for (int j = 0; j < 4; j++) {
        acc[i][j] = __builtin_amdgcn_mfma_f32_16x16x32_bf16(ah[i], bh[j], acc[i][j], 0, 0, 0);
        acc[i][j] = __builtin_amdgcn_mfma_f32_16x16x32_bf16(ah[i], bl[j], acc[i][j], 0, 0, 0);
        acc[i][j] = __builtin_amdgcn_mfma_f32_16x16x32_bf16(al[i], bh[j], acc[i][j], 0, 0, 0);
      }
    cur ^= 1;
  }
#pragma unroll
  for (int i = 0; i < 4; i++) {
    const int row = m0 + wm + i * 16 + lg * 4;
#pragma unroll
    for (int j = 0; j < 4; j++) {
      const int col = n0 + wn + j * 16 + lr;
#pragma unroll
      for (int r = 0; r < 4; r++)
        C[(size_t)(row + r) * 3072 + col] = acc[i][j][r];
    }
  }
}

// ---------------- GEMM C[M,N] = A[M,K]bf16 * BT[N,K]bf16 (+residual) ----------------
template <int MODE>
__launch_bounds__(256, 4)
__global__ void gemm_bt(const u16* __restrict__ A, const u16* __restrict__ BT,
                        float* __restrict__ C, const float* __restrict__ addf,
                        int N, int K) {
  __shared__ __align__(16) u16 Albuf[2][128 * 32];
  __shared__ __align__(16) u16 Blbuf[2][128 * 32];
  const int tid = threadIdx.x;
  const int wid = tid >> 6, lane = tid & 63, lr = lane & 15, lg = lane >> 4;
  const int m0 = blockIdx.x * 128, n0 = blockIdx.y * 128;
  const int wm = (wid >> 1) * 64, wn = (wid & 1) * 64;
  const int c0 = tid, c1 = tid + 256;
  const int ss0 = ((c0 & 3) ^ ((c0 >> 3) & 3)) * 8;
  const int ss1 = ((c1 & 3) ^ ((c1 >> 3) & 3)) * 8;
  const int fs = (lg ^ ((lr >> 1) & 3)) * 8;
  const u16* a0 = A + (size_t)(m0 + (c0 >> 2)) * K + ss0;
  const u16* a1 = A + (size_t)(m0 + (c1 >> 2)) * K + ss1;
  const u16* b0 = BT + (size_t)(n0 + (c0 >> 2)) * K + ss0;
  const u16* b1 = BT + (size_t)(n0 + (c1 >> 2)) * K + ss1;
  f32x4 zv = {0.f, 0.f, 0.f, 0.f};
  f32x4 acc[4][4];
#pragma unroll
  for (int i = 0; i < 4; i++)
#pragma unroll
    for (int j = 0; j < 4; j++) acc[i][j] = zv;
  const int NT = K >> 5;
  gll16(a0, &Albuf[0][c0 * 8]); gll16(a1, &Albuf[0][c1 * 8]);
  gll16(b0, &Blbuf[0][c0 * 8]); gll16(b1, &Blbuf[0][c1 * 8]);
  int cur = 0;
  for (int t = 0; t < NT; ++t) {
    __syncthreads();
    if (t + 1 < NT) {
      int ko = (t + 1) << 5;
      gll16(a0 + ko, &Albuf[cur ^ 1][c0 * 8]); gll16(a1 + ko, &Albuf[cur ^ 1][c1 * 8]);
      gll16(b0 + ko, &Blbuf[cur ^ 1][c0 * 8]); gll16(b1 + ko, &Blbuf[cur ^ 1][c1 * 8]);
    }
    bf16x8 af[4], bf[4];
#pragma unroll
    for (int i = 0; i < 4; i++) af[i] = *(const bf16x8*)&Albuf[cur][(wm + i * 16 + lr) * 32 + fs];
#pragma unroll
    for (int j = 0; j < 4; j++) bf[j] = *(const bf16x8*)&Blbuf[cur][(wn + j * 16 + lr) * 32 + fs];
#pragma unroll
    for (int i = 0; i < 4; i++)
#pragma unroll
      for (int j = 0; j < 4; j++)
        acc[i][j] = __builtin_amdgcn_mfma_f32_16x16x32_bf16(af[i], bf[j], acc[i][j], 0, 0, 0);
    cur ^= 1;
  }
#pragma unroll
  for (int i = 0; i < 4; i++) {
    const int row = m0 + wm + i * 16 + lg * 4;
#pragma unroll
    for (int j = 0; j < 4; j++) {
      const int col = n0 + wn + j * 16 + lr;
#pragma unroll
      for (int r = 0; r < 4; r++) {
        float v = acc[i][j][r];
        if (MODE == 1) v += addf[(size_t)(row + r) * N + col];
        C[(size_t)(row + r) * N + col] = v;
      }
    }
  }
}

// ---------------- RoPE + bf16 hi/lo pack of q/k, bf16 v ----------------
__global__ void k_rope(const int* __restrict__ pos, const float* __restrict__ qkvf,
                       u16* __restrict__ qhi, u16* __restrict__ qlo,
                       u16* __restrict__ khi, u16* __restrict__ klo,
                       u16* __restrict__ vb) {
  __shared__ float invtab[64];
  const int t = blockIdx.x, tid = threadIdx.x;
  if (tid < 64) invtab[tid] = 1.0f / (float)pow(1.0e6, (double)tid / 64.0);
  __syncthreads();
  const float p = (float)pos[t];
  const float* src = qkvf + (size_t)t * 3072;
#pragma unroll
  for (int it = 0; it < 4; ++it) {
    int idx = tid + it * 256;
    int head = idx >> 6, i = idx & 63;
    float ang = p * invtab[i];
    float cc, ssn;
    sincosf(ang, &ssn, &cc);
    float x1 = src[head * 128 + i], x2 = src[head * 128 + i + 64];
    float y1 = x1 * cc - x2 * ssn;
    float y2 = x2 * cc + x1 * ssn;
    u16 h1 = f2b(y1), h2 = f2b(y2);
    size_t o1 = (size_t)t * 2048 + head * 128 + i;
    qhi[o1] = h1;      qlo[o1] = f2b(y1 - b2f(h1));
    qhi[o1 + 64] = h2; qlo[o1 + 64] = f2b(y2 - b2f(h2));
  }
  {
    int head = tid >> 6, i = tid & 63;
    float ang = p * invtab[i];
    float cc, ssn;
    sincosf(ang, &ssn, &cc);
    float x1 = src[2048 + head * 128 + i], x2 = src[2048 + head * 128 + i + 64];
    float y1 = x1 * cc - x2 * ssn;
    float y2 = x2 * cc + x1 * ssn;
    u16 h1 = f2b(y1), h2 = f2b(y2);
    size_t o1 = (size_t)t * 512 + head * 128 + i;
    khi[o1] = h1;      klo[o1] = f2b(y1 - b2f(h1));
    khi[o1 + 64] = h2; klo[o1 + 64] = f2b(y2 - b2f(h2));
  }
#pragma unroll
  for (int u = 0; u < 2; ++u) {
    int ccol = tid + u * 256;
    vb[(size_t)t * 512 + ccol] = f2b(src[2560 + ccol]);
  }
}

// ---------------- tiny f32 helpers for the accurate gate path ----------------
__global__ void k_G(const float* __restrict__ ln2w, const float* __restrict__ gw,
                    float* __restrict__ G) {
  int i = blockIdx.x * 256 + threadIdx.x;   // 2048*8
  G[i] = ln2w[i >> 3] * gw[i];
}
__global__ void k_WG(const float* __restrict__ wo, const float* __restrict__ G,
                     float* __restrict__ WG) {
  int i = blockIdx.x * 256 + threadIdx.x;   // 2048*8
  int r = i >> 3, e = i & 7;
  const float* wr_ = wo + (size_t)r * 2048;
  float s0 = 0, s1 = 0, s2 = 0, s3 = 0;
  for (int c = 0; c < 2048; c += 4) {
    s0 += wr_[c] * G[c * 8 + e];
    s1 += wr_[c + 1] * G[(c + 1) * 8 + e];
    s2 += wr_[c + 2] * G[(c + 2) * 8 + e];
    s3 += wr_[c + 3] * G[(c + 3) * 8 + e];
  }
  WG[i] = (s0 + s1) + (s2 + s3);
}
__global__ void k_resG(const float* __restrict__ resf, const float* __restrict__ G,
                       float* __restrict__ resG) {
  int i = blockIdx.x * 256 + threadIdx.x;   // 2048*8
  int t = i >> 3, e = i & 7;
  const float* rr = resf + (size_t)t * 2048;
  float s0 = 0, s1 = 0, s2 = 0, s3 = 0;
  for (int c = 0; c < 2048; c += 4) {
    s0 += rr[c] * G[c * 8 + e];
    s1 += rr[c + 1] * G[(c + 1) * 8 + e];
    s2 += rr[c + 2] * G[(c + 2) * 8 + e];
    s3 += rr[c + 3] * G[(c + 3) * 8 + e];
  }
  resG[i] = (s0 + s1) + (s2 + s3);
}
__global__ void k_VG(const float* __restrict__ qkvf, const float* __restrict__ WG,
                     float* __restrict__ VG) {
  int i = blockIdx.x * 256 + threadIdx.x;   // 16*2048*8
  int e = i & 7, t = (i >> 3) & 2047, h = i >> 14;
  const float* vr = qkvf + (size_t)t * 3072 + 2560 + (h >> 2) * 128;
  const float* wgr = WG + (size_t)(h * 128) * 8 + e;
  float s = 0;
#pragma unroll 4
  for (int d = 0; d < 128; d++) s += vr[d] * wgr[d * 8];
  VG[i] = s;   // layout [h][t][e]
}

// ---------------- merged flash attention ----------------
__launch_bounds__(256, 2)
__global__ void k_attn2(const u16* __restrict__ qh, const u16* __restrict__ qlo,
                        const u16* __restrict__ kh, const u16* __restrict__ klo,
                        const u16* __restrict__ vb, const float* __restrict__ vg,
                        u16* __restrict__ attnb, float* __restrict__ pvgp) {
  __shared__ __align__(16) u16 Kh[64 * 128];
  __shared__ __align__(16) u16 Kl[64 * 128];
  __shared__ __align__(16) u16 VTl[128 * 64];
  __shared__ __align__(16) u16 Pl[4][16 * 72];
  const int tid = threadIdx.x, wid = tid >> 6, lane = tid & 63, lr = lane & 15, lg = lane >> 4;
  const int h = blockIdx.y, hk = h >> 2, wr = wid * 16;
  f32x4 zv = {0.f, 0.f, 0.f, 0.f};

  for (int half = 0; half < 2; ++half) {
    const int qt = half ? blockIdx.x : 31 - blockIdx.x;   // pair {31-x, x}
    const int q0 = qt * 64;
    float m_[4], l_[4], avg[4][8];
    f32x4 accO[8];
#pragma unroll
    for (int r = 0; r < 4; r++) {
      m_[r] = -3e38f; l_[r] = 0.f;
#pragma unroll
      for (int e = 0; e < 8; e++) avg[r][e] = 0.f;
    }
#pragma unroll
    for (int d = 0; d < 8; d++) accO[d] = zv;
    bf16x8 aqh[4], aql[4];
    {
      const size_t qb = (size_t)(q0 + wr + lr) * 2048 + h * 128 + lg * 8;
#pragma unroll
      for (int kk = 0; kk < 4; kk++) {
        aqh[kk] = *(const bf16x8*)(qh + qb + kk * 32);
        aql[kk] = *(const bf16x8*)(qlo + qb + kk * 32);
      }
    }
    const int nk = qt + 1;
    for (int kt = 0; kt < nk; ++kt) {
      const int s0 = kt * 64;
      __syncthreads();
#pragma unroll
      for (int i = 0; i < 4; i++) {
        int c = tid + i * 256;
        int s = c >> 4, b = (c & 15) * 8;
        size_t go = (size_t)(s0 + s) * 512 + hk * 128 + (b ^ ((s & 7) << 3));
        gll16(kh + go, &Kh[c * 8]);
        gll16(klo + go, &Kl[c * 8]);
      }
      {
        int s = tid >> 2;
        const u16* vsrc = vb + (size_t)(s0 + s) * 512 + hk * 128 + (tid & 3) * 32;
#pragma unroll
        for (int u = 0; u < 4; u++) {
          uint4 wv = *(const uint4*)(vsrc + u * 8);
          const u16* tp = (const u16*)&wv;
          int d0b = (tid & 3) * 32 + u * 8;
          int scol = s ^ (((d0b >> 3) & 7) << 3);
#pragma unroll
          for (int ii = 0; ii < 8; ii++) VTl[(d0b + ii) * 64 + scol] = tp[ii];
        }
      }
      float vgr[4][8];
#pragma unroll
      for (int ct = 0; ct < 4; ct++) {
        const float* vp = vg + ((size_t)h * 2048 + s0 + ct * 16 + lr) * 8;
        float4 u0 = *(const float4*)vp;
        float4 u1 = *(const float4*)(vp + 4);
        vgr[ct][0] = u0.x; vgr[ct][1] = u0.y; vgr[ct][2] = u0.z; vgr[ct][3] = u0.w;
        vgr[ct][4] = u1.x; vgr[ct][5] = u1.y; vgr[ct][6] = u1.z; vgr[ct][7] = u1.w;
      }
      __syncthreads();
      f32x4 accS[4];
#pragma unroll
      for (int ct = 0; ct < 4; ct++) accS[ct] = zv;
      __builtin_amdgcn_s_setprio(1);
#pragma unroll
      for (int kk = 0; kk < 4; kk++) {
#pragma unroll
        for (int ct = 0; ct < 4; ct++) {
          int off = (ct * 16 + lr) * 128 + ((kk * 32 + lg * 8) ^ ((lr & 7) << 3));
          bf16x8 bh = *(const bf16x8*)&Kh[off];
          bf16x8 bl = *(const bf16x8*)&Kl[off];
          accS[ct] = __builtin_amdgcn_mfma_f32_16x16x32_bf16(aqh[kk], bh, accS[ct], 0, 0, 0);
          accS[ct] = __builtin_amdgcn_mfma_f32_16x16x32_bf16(aqh[kk], bl, accS[ct], 0, 0, 0);
          accS[ct] = __builtin_amdgcn_mfma_f32_16x16x32_bf16(aql[kk], bh, accS[ct], 0, 0, 0);
        }
      }
      __builtin_amdgcn_s_setprio(0);
      const bool diag = (kt == qt);
      float alpha[4];
#pragma unroll
      for (int r = 0; r < 4; r++) {
        float sv[4];
        float mx = -3e38f;
#pragma unroll
        for (int ct = 0; ct < 4; ct++) {
          float sc = accS[ct][r] * 0.08838834764831845f;
          if (diag) {
            int col = ct * 16 + lr;
            int row = wr + lg * 4 + r;
            if (col > row) sc = -3e38f;
          }
          sv[ct] = sc; mx = fmaxf(mx, sc);
        }
#pragma unroll
        for (int m2 = 1; m2 < 16; m2 <<= 1) mx = fmaxf(mx, __shfl_xor(mx, m2));
        float mnew = fmaxf(m_[r], mx);
        float a = expf(m_[r] - mnew);
        float pv[4];
        float rs = 0.f;
#pragma unroll
        for (int ct = 0; ct < 4; ct++) { pv[ct] = expf(sv[ct] - mnew); rs += pv[ct]; }
#pragma unroll
        for (int m2 = 1; m2 < 16; m2 <<= 1) rs += __shfl_xor(rs, m2);
        l_[r] = l_[r] * a + rs;
        m_[r] = mnew;
        alpha[r] = a;
#pragma unroll
        for (int e = 0; e < 8; e++) avg[r][e] *= a;
#pragma unroll
        for (int ct = 0; ct < 4; ct++) {
          Pl[wid][(lg * 4 + r) * 72 + ct * 16 + lr] = f2b(pv[ct]);
#pragma unroll
          for (int e = 0; e < 8; e++) avg[r][e] += pv[ct] * vgr[ct][e];
        }
      }
#pragma unroll
      for (int d = 0; d < 8; d++)
#pragma unroll
        for (int r = 0; r < 4; r++) accO[d][r] *= alpha[r];
      // no barrier: Pl[wid] same-wave; VTl covered by post-staging barrier
      __builtin_amdgcn_s_setprio(1);
#pragma unroll
      for (int ks = 0; ks < 2; ks++) {
        bf16x8 ap = *(const bf16x8*)&Pl[wid][lr * 72 + ks * 32 + lg * 8];
#pragma unroll
        for (int d0 = 0; d0 < 8; d0++) {
          int d = d0 * 16 + lr;
          int scol = (ks * 32 + lg * 8) ^ (((d >> 3) & 7) << 3);
          bf16x8 bv = *(const bf16x8*)&VTl[d * 64 + scol];
          accO[d0] = __builtin_amdgcn_mfma_f32_16x16x32_bf16(ap, bv, accO[d0], 0, 0, 0);
        }
      }
      __builtin_amdgcn_s_setprio(0);
    }
#pragma unroll
    for (int d0 = 0; d0 < 8; d0++)
#pragma unroll
      for (int r = 0; r < 4; r++) {
        float v = accO[d0][r] / l_[r];
        attnb[(size_t)(q0 + wr + lg * 4 + r) * 2048 + h * 128 + d0 * 16 + lr] = f2b(v);
      }
#pragma unroll
    for (int m2 = 1; m2 < 16; m2 <<= 1)
#pragma unroll
      for (int r = 0; r < 4; r++)
#pragma unroll
        for (int e = 0; e < 8; e++) avg[r][e] += __shfl_xor(avg[r][e], m2);
#pragma unroll
    for (int r = 0; r < 4; r++) {
      int t = q0 + wr + lg * 4 + r;
      float inv = 1.f / l_[r];
#pragma unroll
      for (int e = 0; e < 8; e++)
        if (lr == e) pvgp[((size_t)h * 2048 + t) * 8 + e] = avg[r][e] * inv;
    }
  }
}

// ---------------- RMSNorm(ln2) + accurate-logit gate + top2 routing ----------------
__global__ void k_ln2gate(const float* __restrict__ res2, const float* __restrict__ w,
                          const float* __restrict__ resG, const float* __restrict__ pvgp,
                          u16* __restrict__ h2b,
                          int* __restrict__ cnt, int* __restrict__ tok,
                          float* __restrict__ wgt, int* __restrict__ jid) {
  const int t = blockIdx.x, tid = threadIdx.x, lane = tid & 63, wid = tid >> 6;
  __shared__ float red[4];
  const size_t base = (size_t)t * Hh;
  float4 r1 = *(const float4*)(res2 + base + tid * 4);
  float4 r2 = *(const float4*)(res2 + base + 1024 + tid * 4);
  float ss = r1.x*r1.x + r1.y*r1.y + r1.z*r1.z + r1.w*r1.w
           + r2.x*r2.x + r2.y*r2.y + r2.z*r2.z + r2.w*r2.w;
#pragma unroll
  for (int m = 1; m < 64; m <<= 1) ss += __shfl_xor(ss, m);
  if (lane == 0) red[wid] = ss;
  __syncthreads();
  float tot = red[0] + red[1] + red[2] + red[3];
  float rstd = rsqrtf(tot * (1.f / Hh) + 1e-5f);
  float4 w1v = *(const float4*)(w + tid * 4);
  float4 w2v = *(const float4*)(w + 1024 + tid * 4);
  ushort4 o1, o2;
  o1.x = f2b(r1.x * rstd * w1v.x); o1.y = f2b(r1.y * rstd * w1v.y);
  o1.z = f2b(r1.z * rstd * w1v.z); o1.w = f2b(r1.w * rstd * w1v.w);
  o2.x = f2b(r2.x * rstd * w2v.x); o2.y = f2b(r2.y * rstd * w2v.y);
  o2.z = f2b(r2.z * rstd * w2v.z); o2.w = f2b(r2.w * rstd * w2v.w);
  *(ushort4*)(h2b + base + tid * 4) = o1;
  *(ushort4*)(h2b + base + 1024 + tid * 4) = o2;
  if (tid == 0) {
    float lg8[8];
#pragma unroll
    for (int e = 0; e < 8; e++) {
      float s = resG[t * 8 + e];
      for (int hh = 0; hh < 16; hh++) s += pvgp[((size_t)hh * 2048 + t) * 8 + e];
      lg8[e] = s * rstd;
    }
    float mx = lg8[0];
#pragma unroll
    for (int e = 1; e < 8; e++) mx = fmaxf(mx, lg8[e]);
    float ex[8];
#pragma unroll
    for (int e = 0; e < 8; e++) ex[e] = expf(lg8[e] - mx);
    int i1 = 0; float v1 = ex[0];
#pragma unroll
    for (int e = 1; e < 8; e++) if (ex[e] > v1) { v1 = ex[e]; i1 = e; }
    int i2 = -1; float v2 = -1.f;
#pragma unroll
    for (int e = 0; e < 8; e++) if (e != i1 && ex[e] > v2) { v2 = ex[e]; i2 = e; }
    float inv = 1.f / (v1 + v2);
    int s1 = atomicAdd(&cnt[i1], 1);
    tok[i1 * 2048 + s1] = t; wgt[i1 * 2048 + s1] = v1 * inv; jid[i1 * 2048 + s1] = 0;
    int s2 = atomicAdd(&cnt[i2], 1);
    tok[i2 * 2048 + s2] = t; wgt[i2 * 2048 + s2] = v2 * inv; jid[i2 * 2048 + s2] = 1;
  }
}

// ---------------- MoE GEMM1, fused half-tile: per block 128M x (64 w1-cols + 64 w3-cols),
// silu fuse in-register. acc = 4x2+4x2 f32x4 = 64 regs (same as single-B kernel);
// 16 MFMA + 4 gll16 per K-step (same density); no x1 scratch round-trip. ----------------
__launch_bounds__(256, 4)
__global__ void gemm13f(const u16* __restrict__ h2b, const u16* __restrict__ w1T,
                        const u16* __restrict__ w3T, u16* __restrict__ gbuf,
                        const int* __restrict__ cnt, const int* __restrict__ tok) {
  const int e = blockIdx.z;
  const int cnt_e = cnt[e];
  const int m0 = blockIdx.y * 128;
  if (m0 >= cnt_e) return;
  int gb = 0;
#pragma unroll
  for (int i = 0; i < 8; i++) if (i < e) gb += cnt[i];
  __shared__ __align__(16) u16 Al[2][128 * 32];
  __shared__ __align__(16) u16 B1l[2][64 * 32];
  __shared__ __align__(16) u16 B3l[2][64 * 32];
  const int tid = threadIdx.x;
  const int wid = tid >> 6, lane = tid & 63, lr = lane & 15, lg = lane >> 4;
  const int n0 = blockIdx.x * 64;
  const int wm = (wid >> 1) * 64, wn = (wid & 1) * 32;
  const int c0 = tid, c1 = tid + 256;
  const int ss0 = ((c0 & 3) ^ ((c0 >> 3) & 3)) * 8;
  const int ss1 = ((c1 & 3) ^ ((c1 >> 3) & 3)) * 8;
  const int fs = (lg ^ ((lr >> 1) & 3)) * 8;
  int r0 = m0 + (c0 >> 2); if (r0 > cnt_e - 1) r0 = cnt_e - 1;
  int r1 = m0 + (c1 >> 2); if (r1 > cnt_e - 1) r1 = cnt_e - 1;
  const int tk0 = tok[e * 2048 + r0], tk1 = tok[e * 2048 + r1];
  const u16* a0 = h2b + (size_t)tk0 * 2048 + ss0;
  const u16* a1 = h2b + (size_t)tk1 * 2048 + ss1;
  const size_t wbase = (size_t)e * DFFd * 2048 + (size_t)(n0 + (c0 >> 2)) * 2048 + ss0;
  const u16* b1p = w1T + wbase;
  const u16* b3p = w3T + wbase;
  f32x4 zv = {0.f, 0.f, 0.f, 0.f};
  f32x4 acc1[4][2], acc3[4][2];
#pragma unroll
  for (int i = 0; i < 4; i++)
#pragma unroll
    for (int j = 0; j < 2; j++) { acc1[i][j] = zv; acc3[i][j] = zv; }
  const int NT = 2048 >> 5;
  gll16(a0, &Al[0][c0 * 8]); gll16(a1, &Al[0][c1 * 8]);
  gll16(b1p, &B1l[0][c0 * 8]); gll16(b3p, &B3l[0][c0 * 8]);
  int cur = 0;
  for (int t = 0; t < NT; ++t) {
    __syncthreads();
    if (t + 1 < NT) {
      int ko = (t + 1) << 5;
      gll16(a0 + ko, &Al[cur ^ 1][c0 * 8]); gll16(a1 + ko, &Al[cur ^ 1][c1 * 8]);
      gll16(b1p + ko, &B1l[cur ^ 1][c0 * 8]); gll16(b3p + ko, &B3l[cur ^ 1][c0 * 8]);
    }
    bf16x8 af[4], b1f[2], b3f[2];
#pragma unroll
    for (int i = 0; i < 4; i++) af[i] = *(const bf16x8*)&Al[cur][(wm + i * 16 + lr) * 32 + fs];
#pragma unroll
    for (int j = 0; j < 2; j++) {
      b1f[j] = *(const bf16x8*)&B1l[cur][(wn + j * 16 + lr) * 32 + fs];
      b3f[j] = *(const bf16x8*)&B3l[cur][(wn + j * 16 + lr) * 32 + fs];
    }
#pragma unroll
    for (int i = 0; i < 4; i++)
#pragma unroll
      for (int j = 0; j < 2; j++) {
        acc1[i][j] = __builtin_amdgcn_mfma_f32_16x16x32_bf16(af[i], b1f[j], acc1[i][j], 0, 0, 0);
        acc3[i][j] = __builtin_amdgcn_mfma_f32_16x16x32_bf16(af[i], b3f[j], acc3[i][j], 0, 0, 0);
      }
    cur ^= 1;
  }
#pragma unroll
  for (int i = 0; i < 4; i++) {
    const int slotb = m0 + wm + i * 16 + lg * 4;
#pragma unroll
    for (int j = 0; j < 2; j++) {
      const int col = n0 + wn + j * 16 + lr;
#pragma unroll
      for (int r = 0; r < 4; r++) {
        int slot = slotb + r;
        if (slot < cnt_e) {
          float xv = acc1[i][j][r];
          float g = xv / (1.f + __expf(-xv)) * acc3[i][j][r];
          gbuf[(size_t)(gb + slot) * DFFd + col] = f2b(g);
        }
      }
    }
  }
}

// ---------------- MoE GEMM2 split-K: out = w * (g @ w2), K=4096 -> 2x2048.
// blockIdx.y encodes (m-tile, k-half); partials go to outk (kh=0) / outkx (kh=1). ----------------
__launch_bounds__(256, 4)
__global__ void gemm2k(const u16* __restrict__ gbuf, const u16* __restrict__ w2T,
                       float* __restrict__ outk, float* __restrict__ outkx,
                       const int* __restrict__ cnt,
                       const int* __restrict__ tok, const float* __restrict__ wgt,
                       const int* __restrict__ jid) {
  const int e = blockIdx.z;
  const int cnt_e = cnt[e];
  const int kh = blockIdx.y & 1;
  const int m0 = (blockIdx.y >> 1) * 128;
  if (m0 >= cnt_e) return;
  int gb = 0;
#pragma unroll
  for (int i = 0; i < 8; i++) if (i < e) gb += cnt[i];
  __shared__ __align__(16) u16 Al[2][128 * 32];
  __shared__ __align__(16) u16 Bl[2][128 * 32];
  const int tid = threadIdx.x;
  const int wid = tid >> 6, lane = tid & 63, lr = lane & 15, lg = lane >> 4;
  const int n0 = blockIdx.x * 128;
  const int wm = (wid >> 1) * 64, wn = (wid & 1) * 64;
  const int c0 = tid, c1 = tid + 256;
  const int ss0 = ((c0 & 3) ^ ((c0 >> 3) & 3)) * 8;
  const int ss1 = ((c1 & 3) ^ ((c1 >> 3) & 3)) * 8;
  const int fs = (lg ^ ((lr >> 1) & 3)) * 8;
  const int k0 = kh * 2048;
  const u16* A = gbuf + (size_t)gb * DFFd + k0;
  const u16* a0 = A + (size_t)(m0 + (c0 >> 2)) * DFFd + ss0;
  const u16* a1 = A + (size_t)(m0 + (c1 >> 2)) * DFFd + ss1;
  const u16* b0 = w2T + (size_t)e * 2048 * DFFd + (size_t)(n0 + (c0 >> 2)) * DFFd + k0 + ss0;
  const u16* b1 = w2T + (size_t)e * 2048 * DFFd + (size_t)(n0 + (c1 >> 2)) * DFFd + k0 + ss1;
  f32x4 zv = {0.f, 0.f, 0.f, 0.f};
  f32x4 acc[4][4];
#pragma unroll
  for (int i = 0; i < 4; i++)
#pragma unroll
    for (int j = 0; j < 4; j++) acc[i][j] = zv;
  const int NT = 2048 >> 5;
  gll16(a0, &Al[0][c0 * 8]); gll16(a1, &Al[0][c1 * 8]);
  gll16(b0, &Bl[0][c0 * 8]); gll16(b1, &Bl[0][c1 * 8]);
  int cur = 0;
  for (int t = 0; t < NT; ++t) {
    __syncthreads();
    if (t + 1 < NT) {
      int ko = (t + 1) << 5;
      gll16(a0 + ko, &Al[cur ^ 1][c0 * 8]); gll16(a1 + ko, &Al[cur ^ 1][c1 * 8]);
      gll16(b0 + ko, &Bl[cur ^ 1][c0 * 8]); gll16(b1 + ko, &Bl[cur ^ 1][c1 * 8]);
    }
    bf16x8 af[4], bf[4];
#pragma unroll
    for (int i = 0; i < 4; i++) af[i] = *(const bf16x8*)&Al[cur][(wm + i * 16 + lr) * 32 + fs];
#pragma unroll
    for (int j = 0; j < 4; j++) bf[j] = *(const bf16x8*)&Bl[cur][(wn + j * 16 + lr) * 32 + fs];
#pragma unroll
    for (int i = 0; i < 4; i++)
#pragma unroll
      for (int j = 0; j < 4; j++)
        acc[i][j] = __builtin_amdgcn_mfma_f32_16x16x32_bf16(af[i], bf[j], acc[i][j], 0, 0, 0);
    cur ^= 1;
  }
  float* basep = kh ? outkx : outk;
#pragma unroll
  for (int i = 0; i < 4; i++) {
    const int slotb = m0 + wm + i * 16 + lg * 4;
#pragma unroll
    for (int r = 0; r < 4; r++) {
      int slot = slotb + r;
      if (slot < cnt_e) {
        int tkn = tok[e * 2048 + slot];
        float wv = wgt[e * 2048 + slot];
        int jj = jid[e * 2048 + slot];
        float* orow = basep + (size_t)jj * ((size_t)Tt * Hh) + (size_t)tkn * Hh;
#pragma unroll
        for (int j = 0; j < 4; j++) {
          const int col = n0 + wn + j * 16 + lr;
          orow[col] = wv * acc[i][j][r];
        }
      }
    }
  }
}

__global__ void k_zero(int* cnt) { if (threadIdx.x < 8) cnt[threadIdx.x] = 0; }

__global__ void k_combine(const float* __restrict__ outk, const float* __restrict__ outkx,
                          float* __restrict__ dout) {
  size_t i = ((size_t)blockIdx.x * 256 + threadIdx.x) * 4;
  float4 a = *(const float4*)(outk + i);
  float4 b = *(const float4*)(outk + (size_t)Tt * Hh + i);
  float4 c = *(const float4*)(outkx + i);
  float4 d = *(const float4*)(outkx + (size_t)Tt * Hh + i);
  float4 o = {a.x + b.x + c.x + d.x, a.y + b.y + c.y + d.y,
              a.z + b.z + c.z + d.z, a.w + b.w + c.w + d.w};
  *(float4*)(dout + i) = o;
}

extern "C" void kernel_launch(void* const* d_in, const int* in_sizes, int n_in,
                              void* d_out, int out_size, void* d_ws, size_t ws_size,
                              hipStream_t stream) {
  const int*   positions = (const int*)d_in[0];
  const float* hs    = (const float*)d_in[1];
  const float* resid = (const float*)d_in[2];
  const float* ln1w  = (const float*)d_in[3];
  const float* ln2w  = (const float*)d_in[4];
  const float* wq    = (const float*)d_in[5];
  const float* wk    = (const float*)d_in[6];
  const float* wv    = (const float*)d_in[7];
  const float* wo    = (const float*)d_in[8];
  const float* gatew = (const float*)d_in[9];
  const float* w1    = (const float*)d_in[10];
  const float* w3    = (const float*)d_in[11];
  const float* w2    = (const float*)d_in[12];
  float* dout = (float*)d_out;
  float* res2 = dout + (size_t)Tt * Hh;

  char* wp = (char*)d_ws;
  auto take = [&](size_t bytes) -> void* {
    void* p = (void*)wp;
    wp += (bytes + 255) & ~(size_t)255;
    return p;
  };
  u16*   qkvT  = (u16*)  take((size_t)3072 * 2048 * 2);
  u16*   qkvTl = (u16*)  take((size_t)3072 * 2048 * 2);
  u16*   woT   = (u16*)  take((size_t)2048 * 2048 * 2);
  u16*   w1T   = (u16*)  take((size_t)8 * 4096 * 2048 * 2);
  u16*   w3T   = (u16*)  take((size_t)8 * 4096 * 2048 * 2);
  u16*   w2T   = (u16*)  take((size_t)8 * 2048 * 4096 * 2);
  float* resf  = (float*)take((size_t)Tt * Hh * 4);            // 16 MB ┐ dead after gemm_bt<1>;
  u16*   hb    = (u16*)  take((size_t)Tt * Hh * 2);            //  8 MB │ reused as outkx (2 f32
  u16*   hblo  = (u16*)  take((size_t)Tt * Hh * 2);            //  8 MB ┘ planes = 32 MB exactly)
  float* qkvf  = (float*)take((size_t)Tt * 3072 * 4);
  u16*   qhi   = (u16*)  take((size_t)Tt * 2048 * 2);
  u16*   qlo   = (u16*)  take((size_t)Tt * 2048 * 2);
  u16*   khi   = (u16*)  take((size_t)Tt * 512 * 2);
  u16*   klo   = (u16*)  take((size_t)Tt * 512 * 2);
  u16*   vb2   = (u16*)  take((size_t)Tt * 512 * 2);
  u16*   attnb = (u16*)  take((size_t)Tt * 2048 * 2);
  u16*   h2b   = (u16*)  take((size_t)Tt * Hh * 2);
  u16*   gbuf  = (u16*)  take((size_t)(4096 + 128) * 4096 * 2);
  float* outk  = (float*)take((size_t)2 * Tt * Hh * 4);
  float* Gb    = (float*)take((size_t)2048 * 8 * 4);
  float* WGb   = (float*)take((size_t)2048 * 8 * 4);
  float* resGb = (float*)take((size_t)Tt * 8 * 4);
  float* VGb   = (float*)take((size_t)16 * Tt * 8 * 4);
  float* pvgp  = (float*)take((size_t)16 * Tt * 8 * 4);
  int*   tok   = (int*)  take((size_t)8 * 2048 * 4);
  float* wgt   = (float*)take((size_t)8 * 2048 * 4);
  int*   jid   = (int*)  take((size_t)8 * 2048 * 4);
  int*   cnt   = (int*)  take(64);
  if ((size_t)(wp - (char*)d_ws) > ws_size) return;
  // outkx (2 planes of Tt*Hh f32 = 32 MB) aliases resf+hb+hblo (16+8+8 = 32 MB),
  // all dead before gemm2k runs.
  float* outkx = resf;

  k_zero<<<1, 64, 0, stream>>>(cnt);
  k_addnorm<<<Tt, 256, 0, stream>>>(hs, resid, ln1w, resf, hb, hblo);
  k_transpose2_64<<<dim3(32, 32, 1), 256, 0, stream>>>(wq, qkvT, qkvTl, 2048, 2048);
  k_transpose2_64<<<dim3(32, 8, 1), 256, 0, stream>>>(wk, qkvT + (size_t)2048 * 2048,
                                                      qkvTl + (size_t)2048 * 2048, 2048, 512);
  k_transpose2_64<<<dim3(32, 8, 1), 256, 0, stream>>>(wv, qkvT + (size_t)2560 * 2048,
                                                      qkvTl + (size_t)2560 * 2048, 2048, 512);
  k_transpose64<<<dim3(32, 32, 1), 256, 0, stream>>>(wo, woT, 2048, 2048);
  k_transpose64<<<dim3(32, 64, 8), 256, 0, stream>>>(w1, w1T, 2048, 4096);
  k_transpose64<<<dim3(32, 64, 8), 256, 0, stream>>>(w3, w3T, 2048, 4096);
  k_transpose64<<<dim3(64, 32, 8), 256, 0, stream>>>(w2, w2T, 4096, 2048);
  k_G<<<64, 256, 0, stream>>>(ln2w, gatew, Gb);
  k_WG<<<64, 256, 0, stream>>>(wo, Gb, WGb);
  k_resG<<<64, 256, 0, stream>>>(resf, Gb, resGb);
  gemm_qkv<<<dim3(16, 24, 1), 256, 0, stream>>>(hb, hblo, qkvT, qkvTl, qkvf);
  k_rope<<<Tt, 256, 0, stream>>>(positions, qkvf, qhi, qlo, khi, klo, vb2);
  k_VG<<<1024, 256, 0, stream>>>(qkvf, WGb, VGb);
  k_attn2<<<dim3(16, 16, 1), 256, 0, stream>>>(qhi, qlo, khi, klo, vb2, VGb, attnb, pvgp);
  gemm_bt<1><<<dim3(16, 16, 1), 256, 0, stream>>>(attnb, woT, res2, resf, 2048, 2048);
  k_ln2gate<<<Tt, 256, 0, stream>>>(res2, ln2w, resGb, pvgp, h2b, cnt, tok, wgt, jid);
  gemm13f<<<dim3(64, 16, 8), 256, 0, stream>>>(h2b, w1T, w3T, gbuf, cnt, tok);
  gemm2k<<<dim3(16, 32, 8), 256, 0, stream>>>(gbuf, w2T, outk, outkx, cnt, tok, wgt, jid);
  k_combine<<<4096, 256, 0, stream>>>(outk, outkx, dout);
}